// Round 8
// baseline (331.862 us; speedup 1.0000x reference)
//
#include <hip/hip_runtime.h>

#define T_ 32
#define B_ 32
#define MAPD 517
#define P_ 256
#define FLATD (MAPD*P_)   // 132352
#define TBN (T_*B_)       // 1024

typedef unsigned short u16;
typedef unsigned int u32;
typedef __attribute__((ext_vector_type(4))) short short4v;
typedef __attribute__((ext_vector_type(8))) short short8v;
typedef __attribute__((ext_vector_type(4))) float f32x4;
typedef __attribute__((ext_vector_type(2))) float f32x2;
typedef __attribute__((ext_vector_type(4))) u32 u32x4;

__device__ __forceinline__ float bfv(u16 u){ u32 x = ((u32)u)<<16; return __uint_as_float(x); }
__device__ __forceinline__ u16 fbf(float f){
  u32 x = __float_as_uint(f);
  return (u16)((x + 0x7fffu + ((x>>16)&1u))>>16);
}
template<bool F32> __device__ __forceinline__ float ld(const void* p, size_t i){
  if constexpr (F32) return ((const float*)p)[i];
  else               return bfv(((const u16*)p)[i]);
}
__device__ __forceinline__ float ldf(bool f32, const void* p, size_t i){
  return f32 ? ((const float*)p)[i] : bfv(((const u16*)p)[i]);
}

// ---- inline dtype probe: per-wave, no barrier ----
__device__ __forceinline__ bool probe_f32(const void* img){
  int lane = threadIdx.x & 63;
  ushort4 v = ((const ushort4*)img)[lane];      // lanes cover first 256 u16
  int c = (v.x <= 0x4380u) + (v.y <= 0x4380u) + (v.z <= 0x4380u) + (v.w <= 0x4380u);
  #pragma unroll
  for (int off = 32; off > 0; off >>= 1) c += __shfl_xor(c, off, 64);
  return c < 240;
}

// ================= k_A: wt-transpose (1034) + prep (684) + meta (36) =================
template<bool F32> __device__ void wt_body(int lbid, const void* pw1, const void* vw1,
                                           u16* wt, u32* tile){
  int c  = lbid >> 1;
  int ph = lbid & 1;
  for (int it = 0; it < 4; ++it){
    int idx = it*256 + threadIdx.x;        // [0,1024)
    int jp = idx >> 4, pg = idx & 15;      // jp: 64 j-pairs, pg: 16 pp-groups of 8
    int j0 = jp*2;
    const void* w = (j0 < 64) ? pw1 : vw1;
    int jj0 = (j0 < 64) ? j0 : j0-64;
    size_t base0 = (size_t)jj0*FLATD + c*P_ + ph*128 + pg*8;
    size_t base1 = base0 + FLATD;
    u16 a[8], b[8];
    if constexpr (F32){
      const float* f = (const float*)w;
      float4 a0 = *(const float4*)(f + base0), a1 = *(const float4*)(f + base0 + 4);
      float4 b0 = *(const float4*)(f + base1), b1 = *(const float4*)(f + base1 + 4);
      a[0]=fbf(a0.x); a[1]=fbf(a0.y); a[2]=fbf(a0.z); a[3]=fbf(a0.w);
      a[4]=fbf(a1.x); a[5]=fbf(a1.y); a[6]=fbf(a1.z); a[7]=fbf(a1.w);
      b[0]=fbf(b0.x); b[1]=fbf(b0.y); b[2]=fbf(b0.z); b[3]=fbf(b0.w);
      b[4]=fbf(b1.x); b[5]=fbf(b1.y); b[6]=fbf(b1.z); b[7]=fbf(b1.w);
    } else {
      short8v va = *(const short8v*)((const u16*)w + base0);
      short8v vb = *(const short8v*)((const u16*)w + base1);
      #pragma unroll
      for (int k = 0; k < 8; ++k){ a[k] = (u16)va[k]; b[k] = (u16)vb[k]; }
    }
    int slot = (jp >> 2) ^ pg;
    int sub  = jp & 3;
    #pragma unroll
    for (int k = 0; k < 8; ++k){
      int pp = pg*8 + k;
      tile[pp*64 + slot*4 + sub] = (u32)a[k] | ((u32)b[k] << 16);
    }
  }
  __syncthreads();
  for (int it = 0; it < 8; ++it){
    int idx = it*256 + threadIdx.x;        // [0,2048)
    int pp = idx >> 4, jb = idx & 15;
    int slot = jb ^ ((pp >> 3) & 15);
    u32x4 v = *(const u32x4*)(tile + pp*64 + slot*4);
    int p = ph*128 + pp;
    *(u32x4*)(wt + ((size_t)p*MAPD + c)*128 + jb*8) = v;
  }
}

__device__ void prep_body(bool f32, int bid, const void* c1w, const void* c2w, const void* c3w,
                          const void* fcw, const void* st0,
                          u16* W1F, u16* W2F, u16* W3F, u16* FWF, u16* ST0T, char* smem_){
  int tid = threadIdx.x;
  if (bid < 24){
    int idx = bid*256 + tid;                   // 6144
    int j = idx & 7, l = (idx>>3) & 63, t = idx>>9;
    int nt = t/6, s = t - nt*6;
    int oc = nt*16 + (l&15);
    int kk = 8*(4*s + (l>>4)) + j;
    float v = ldf(f32, c1w, oc*192+kk);
    W1F[idx] = fbf(v);
  } else if (bid < 152){
    int idx = (bid-24)*256 + tid;              // 32768
    int j = idx & 7, l = (idx>>3) & 63, s = (idx>>9) & 15, nt = idx>>13;
    int oc = nt*16 + (l&15);
    int cin = (l>>4)*8 + j;
    int src = oc*512 + cin*16 + (s>>2)*4 + (s&3);
    W2F[idx] = fbf(ldf(f32, c2w, src));
  } else if (bid < 296){
    int idx = (bid-152)*256 + tid;             // 36864
    int j = idx & 7, l = (idx>>3) & 63, t = idx>>9;   // t = nt*18+s
    int nt = t/18, s = t - nt*18;
    int oc = nt*16 + (l&15);
    int c = (s&1)*32 + (l>>4)*8 + j;
    int src = oc*576 + c*9 + (s>>1);
    W3F[idx] = fbf(ldf(f32, c3w, src));
  } else if (bid < 424){
    // FWF: MFMA B-fragments of fc_w for fc GEMM.
    int b = bid - 296;                          // 128 blocks x 4096 elems
    for (int it = 0; it < 16; ++it){
      int idx = (b*16 + it)*256 + tid;          // 524288 total
      int j = idx & 7, l = (idx>>3) & 63, frag = idx >> 9;
      int nt = frag >> 5, kt = frag & 31;
      int kc = kt*32 + ((l>>4)<<3) + j;
      int kr = (kc & 63)*16 + (kc >> 6);
      int o  = nt*16 + (l & 15);
      FWF[idx] = fbf(ldf(f32, fcw, (size_t)o*1024 + kr));
    }
  } else {
    // ST0T[p][c][b] transpose — vectorized both sides, pad-36 LDS, rotated write order.
    u16* tile = (u16*)smem_;                   // [ci<4][pl<64] stride 36 u16 + b
    int b0 = bid - 424;                        // 260 blocks
    int c0 = (b0 >> 2)*8, p0 = (b0 & 3)*64;
    for (int half = 0; half < 2; ++half){
      int ch = c0 + half*4;
      for (int it = 0; it < 4; ++it){
        int idx = it*256 + tid;                // [0,1024)
        int pg = idx & 7, b = (idx>>3) & 31, ci = idx >> 8;   // ci 0..3
        int c = ch + ci;
        u16 v[8];
        if (c < MAPD){
          size_t src = ((size_t)b*MAPD + c)*256 + p0 + pg*8;
          if (f32){
            const float* f = (const float*)st0;
            float4 x0 = *(const float4*)(f + src), x1 = *(const float4*)(f + src + 4);
            v[0]=fbf(x0.x); v[1]=fbf(x0.y); v[2]=fbf(x0.z); v[3]=fbf(x0.w);
            v[4]=fbf(x1.x); v[5]=fbf(x1.y); v[6]=fbf(x1.z); v[7]=fbf(x1.w);
          } else {
            short8v x = *(const short8v*)((const u16*)st0 + src);
            #pragma unroll
            for (int k = 0; k < 8; ++k) v[k] = (u16)x[k];
          }
        } else {
          #pragma unroll
          for (int k = 0; k < 8; ++k) v[k] = 0;
        }
        #pragma unroll
        for (int kk = 0; kk < 8; ++kk){
          int k2 = (kk + pg) & 7;
          tile[ci*2304 + (pg*8 + k2)*36 + b] = v[k2];
        }
      }
      __syncthreads();
      for (int it = 0; it < 8; ++it){
        int idx = it*256 + tid;                // [0,2048)
        int bq = idx & 7, pl = (idx>>3) & 63, ci = idx >> 9;  // ci 0..3
        int c = ch + ci;
        if (c < MAPD){
          ushort4 v = *(const ushort4*)(tile + ci*2304 + pl*36 + bq*4);
          *(ushort4*)(ST0T + ((size_t)(p0+pl)*MAPD + c)*32 + bq*4) = v;
        }
      }
      __syncthreads();
    }
  }
}

__device__ void meta_body(bool f32, int bid, const int* pos, const void* done, const int* lact,
                          int* prev, float* coef, float* H, int* lastw, float* lastc){
  if (bid < 4){
    int i = bid*256 + threadIdx.x;
    int t = i >> 5, b = i & 31;
    int p = pos[i*2]*16 + pos[i*2+1];
    int pv = -1;
    for (int s = t-1; s >= 0; --s){
      int n = s*32 + b;
      if (pos[n*2]*16 + pos[n*2+1] == p){ pv = s; break; }
    }
    float cf = 1.f;
    for (int s = (pv<0?0:pv+1); s <= t-1; ++s)
      cf *= (1.f - ldf(f32, done, s*32+b));
    prev[i] = pv; coef[i] = cf;
    int la = lact[i];
    #pragma unroll
    for (int a = 0; a < 5; ++a) H[(size_t)i*MAPD + 512 + a] = (la == a) ? 1.f : 0.f;
  } else {
    int i = (bid-4)*256 + threadIdx.x;
    int b = i >> 8, p = i & 255;
    int lw = -1;
    for (int s = T_-1; s >= 0; --s){
      int n = s*32 + b;
      if (pos[n*2]*16 + pos[n*2+1] == p){ lw = s; break; }
    }
    float cf = 1.f;
    for (int s = (lw<0?0:lw+1); s < T_; ++s)
      cf *= (1.f - ldf(f32, done, s*32+b));
    lastw[i] = lw; lastc[i] = cf;
  }
}

__global__ __launch_bounds__(256) void k_A(const void* image,
                                           const void* pw1, const void* vw1, u16* wt,
                                           const void* c1w, const void* c2w, const void* c3w,
                                           const void* fcw, const void* st0,
                                           u16* W1F, u16* W2F, u16* W3F, u16* FWF, u16* ST0T,
                                           const int* pos, const void* done, const int* lact,
                                           int* prev, float* coef, float* H, int* lastw, float* lastc){
  __shared__ __align__(16) char smem_[32768];
  bool f32 = probe_f32(image);
  int bid = blockIdx.x;
  if (bid < 1034){
    if (f32) wt_body<true>(bid, pw1, vw1, wt, (u32*)smem_);
    else     wt_body<false>(bid, pw1, vw1, wt, (u32*)smem_);
  } else if (bid < 1718){
    prep_body(f32, bid-1034, c1w, c2w, c3w, fcw, st0, W1F, W2F, W3F, FWF, ST0T, smem_);
  } else {
    meta_body(f32, bid-1718, pos, done, lact, prev, coef, H, lastw, lastc);
  }
}

// ================= k_conv123: fused convs =================
__global__ __launch_bounds__(256) void k_conv123(const void* img,
                                                 const u16* __restrict__ W1F, const void* b1,
                                                 const u16* __restrict__ W2F, const void* b2,
                                                 const u16* __restrict__ W3F, const void* b3,
                                                 u16* __restrict__ out){
  __shared__ __align__(16) u16 smem[19488];
  u16* sImg = smem;            // 12288 u16
  u16* sA   = smem + 12288;    // 7200 u16
  u16* sBv  = smem;            // 2304 u16, overlays sImg after conv1
  bool f32 = probe_f32(img);
  int n = blockIdx.x, tid = threadIdx.x;
  if (f32){
    const float4* ip = (const float4*)((const float*)img + (size_t)n*12288);
    for (int i = tid; i < 3072; i += 256){
      float4 v = ip[i];
      ushort4 u; u.x = fbf(v.x); u.y = fbf(v.y); u.z = fbf(v.z); u.w = fbf(v.w);
      int L = i*4;
      int addr = (L & ~63) | (((L & 63) + (((L >> 6) & 3) << 4)) & 63);
      *(ushort4*)(sImg + addr) = u;
    }
  } else {
    const ushort4* ip = (const ushort4*)((const u16*)img + (size_t)n*12288);
    for (int i = tid; i < 3072; i += 256){
      ushort4 u = ip[i];
      int L = i*4;
      int addr = (L & ~63) | (((L & 63) + (((L >> 6) & 3) << 4)) & 63);
      *(ushort4*)(sImg + addr) = u;
    }
  }
  int wv = tid >> 6, lane = tid & 63;
  int mi = lane & 15, q = lane >> 4;

  short8v bfr1[2][6];
  #pragma unroll
  for (int nt = 0; nt < 2; ++nt)
    #pragma unroll
    for (int s = 0; s < 6; ++s)
      bfr1[nt][s] = ((const short8v*)W1F)[(nt*6+s)*64 + lane];
  float b1v[2];
  #pragma unroll
  for (int nt = 0; nt < 2; ++nt)
    b1v[nt] = ldf(f32, b1, nt*16+mi);
  __syncthreads();

  {
    f32x4 acc[4][2];
    #pragma unroll
    for (int mt = 0; mt < 4; ++mt)
      #pragma unroll
      for (int nt = 0; nt < 2; ++nt)
        acc[mt][nt] = (f32x4){0.f,0.f,0.f,0.f};
    int base[4];
    #pragma unroll
    for (int mt = 0; mt < 4; ++mt){
      int m = (wv*4+mt)*16 + mi;
      int mc = m < 225 ? m : 224;
      int oy = mc/15, ox = mc - oy*15;
      base[mt] = oy*256 + ox*4;
    }
    for (int s = 0; s < 6; ++s){
      int cky = 4*s + q;
      int off = (cky >> 3)*4096 + (cky & 7)*64;
      #pragma unroll
      for (int mt = 0; mt < 4; ++mt){
        int Lb = base[mt] + off;
        const u16* rp = sImg + (Lb & ~63);
        int x0 = Lb & 63;
        int rot = ((Lb >> 6) & 3) << 4;
        short4v lo = *(const short4v*)(rp + ((x0 + rot) & 63));
        short4v hi = *(const short4v*)(rp + ((x0 + 4 + rot) & 63));
        short8v a = __builtin_shufflevector(lo, hi, 0,1,2,3,4,5,6,7);
        acc[mt][0] = __builtin_amdgcn_mfma_f32_16x16x32_bf16(a, bfr1[0][s], acc[mt][0], 0,0,0);
        acc[mt][1] = __builtin_amdgcn_mfma_f32_16x16x32_bf16(a, bfr1[1][s], acc[mt][1], 0,0,0);
      }
    }
    __syncthreads();   // sImg reads done before sBv (alias) writes in conv2
    #pragma unroll
    for (int mt = 0; mt < 4; ++mt){
      int mrow0 = (wv*4+mt)*16 + q*4;
      #pragma unroll
      for (int nt = 0; nt < 2; ++nt){
        int oc = nt*16 + mi;
        #pragma unroll
        for (int r = 0; r < 4; ++r){
          int m = mrow0 + r;
          if (m < 225){
            int g = ((oc >> 3) ^ ((m >> 1) & 3)) << 3;
            sA[m*32 + g + (oc & 7)] = fbf(fmaxf(acc[mt][nt][r] + b1v[nt], 0.f));
          }
        }
      }
    }
  }
  __syncthreads();

  {
    short8v bfr2[16];
    #pragma unroll
    for (int s = 0; s < 16; ++s)
      bfr2[s] = ((const short8v*)W2F)[(wv*16+s)*64 + lane];
    int oc = wv*16 + mi;
    float bv = ldf(f32, b2, oc);
    f32x4 acc[3];
    #pragma unroll
    for (int mt = 0; mt < 3; ++mt) acc[mt] = (f32x4){0.f,0.f,0.f,0.f};
    int pixb[3];
    #pragma unroll
    for (int mt = 0; mt < 3; ++mt){
      int m = mt*16 + mi; if (m > 35) m = 35;
      int oy = m/6, ox = m - oy*6;
      pixb[mt] = oy*30 + ox*2;
    }
    #pragma unroll
    for (int s = 0; s < 16; ++s){
      int dp = (s>>2)*15 + (s&3);
      #pragma unroll
      for (int mt = 0; mt < 3; ++mt){
        int pix = pixb[mt] + dp;
        int g = (q ^ ((pix >> 1) & 3)) << 3;
        short8v a = *(const short8v*)(sA + pix*32 + g);
        acc[mt] = __builtin_amdgcn_mfma_f32_16x16x32_bf16(a, bfr2[s], acc[mt], 0,0,0);
      }
    }
    __syncthreads();
    #pragma unroll
    for (int mt = 0; mt < 3; ++mt)
      #pragma unroll
      for (int r = 0; r < 4; ++r){
        int m = mt*16 + q*4 + r;
        if (m < 36){
          int g = ((oc >> 3) ^ (m & 7)) << 3;
          sBv[m*64 + g + (oc & 7)] = fbf(fmaxf(acc[mt][r] + bv, 0.f));
        }
      }
  }
  __syncthreads();

  {
    int oy = mi >> 2, ox = mi & 3;
    int oc = wv*16 + mi;
    float bv = ldf(f32, b3, oc);
    short8v bfr3[18];
    #pragma unroll
    for (int s = 0; s < 18; ++s)
      bfr3[s] = ((const short8v*)W3F)[(wv*18+s)*64 + lane];
    f32x4 acc = (f32x4){0.f,0.f,0.f,0.f};
    #pragma unroll
    for (int s = 0; s < 18; ++s){
      int pair = s >> 1, ky = pair/3, kx = pair - ky*3;
      int pix = (oy+ky)*6 + ox+kx;
      int g = ((((s & 1) << 2) | q) ^ (pix & 7)) << 3;
      short8v a = *(const short8v*)(sBv + pix*64 + g);
      acc = __builtin_amdgcn_mfma_f32_16x16x32_bf16(a, bfr3[s], acc, 0,0,0);
    }
    u16* ob = out + (size_t)n*1024;
    #pragma unroll
    for (int r = 0; r < 4; ++r)
      ob[(q*4+r)*64 + oc] = fbf(fmaxf(acc[r] + bv, 0.f));
  }
}

// ================= k_C: yinit (1024) + fc (512) =================
template<int CLEN>
__device__ __forceinline__ void yloop(const u16* __restrict__ wp, const float* __restrict__ sSb,
                                      float (&acc)[8][2]){
  #pragma unroll 10
  for (int c = 0; c < CLEN; ++c){
    u32 w = *(const u32*)(wp + (size_t)c*128);
    float w0 = bfv((u16)(w & 0xffffu)), w1 = bfv((u16)(w >> 16));
    const float4* s4 = (const float4*)(sSb + c*32);
    float4 sa = s4[0], sb = s4[1];
    float sv[8] = {sa.x,sa.y,sa.z,sa.w,sb.x,sb.y,sb.z,sb.w};
    #pragma unroll
    for (int bb = 0; bb < 8; ++bb){
      acc[bb][0] += sv[bb]*w0;
      acc[bb][1] += sv[bb]*w1;
    }
  }
}
__device__ void yinit_body(int lbid, const u16* __restrict__ ST0T, const u16* __restrict__ wt,
                           u16* __restrict__ PARTB, float* sS){
  int p = lbid >> 2, cq = lbid & 3;
  int c0 = cq*130;
  int clen = (cq == 3) ? 127 : 130;
  const ushort4* ssrc = (const ushort4*)(ST0T + ((size_t)p*MAPD + c0)*32);
  int n4 = clen*8;
  for (int i = threadIdx.x; i < n4; i += 256){
    ushort4 u = ssrc[i];
    float4 f; f.x = bfv(u.x); f.y = bfv(u.y); f.z = bfv(u.z); f.w = bfv(u.w);
    *(float4*)(sS + i*4) = f;
  }
  __syncthreads();
  int jg = threadIdx.x & 63, bg = threadIdx.x >> 6;
  int j0 = jg*2, b0 = bg*8;
  const u16* wp = wt + ((size_t)p*MAPD + c0)*128 + j0;
  float acc[8][2] = {};
  if (cq < 3) yloop<130>(wp, sS + b0, acc);
  else        yloop<127>(wp, sS + b0, acc);
  u32* op = (u32*)(PARTB + (size_t)lbid*4096);
  #pragma unroll
  for (int bb = 0; bb < 8; ++bb){
    u32 pk = (u32)fbf(acc[bb][0]) | ((u32)fbf(acc[bb][1]) << 16);
    op[((b0+bb)*128 + j0) >> 1] = pk;
  }
}
__device__ void fc_body(int lbid, bool f32, const u16* __restrict__ C, const u16* __restrict__ FWF,
                        const void* fb, float* __restrict__ H){
  int wv = threadIdx.x >> 6, lane = threadIdx.x & 63;
  int mi = lane & 15, q = lane >> 4;
  int mt = lbid >> 3;               // 0..63
  int nt = (lbid & 7)*4 + wv;       // 0..31
  const u16* ap = C + (size_t)(mt*16 + mi)*1024 + q*8;
  const short8v* bp = (const short8v*)FWF + (size_t)nt*32*64 + lane;
  f32x4 acc0 = (f32x4){0.f,0.f,0.f,0.f};
  f32x4 acc1 = (f32x4){0.f,0.f,0.f,0.f};
  #pragma unroll
  for (int kt = 0; kt < 32; kt += 2){
    short8v a0 = *(const short8v*)(ap + kt*32);
    short8v b0 = bp[kt*64];
    short8v a1 = *(const short8v*)(ap + (kt+1)*32);
    short8v b1 = bp[(kt+1)*64];
    acc0 = __builtin_amdgcn_mfma_f32_16x16x32_bf16(a0, b0, acc0, 0,0,0);
    acc1 = __builtin_amdgcn_mfma_f32_16x16x32_bf16(a1, b1, acc1, 0,0,0);
  }
  int o = nt*16 + mi;
  float bv = ldf(f32, fb, o);
  #pragma unroll
  for (int r = 0; r < 4; ++r){
    int m = mt*16 + q*4 + r;
    H[(size_t)m*MAPD + o] = fmaxf(acc0[r] + acc1[r] + bv, 0.f);
  }
}
__global__ __launch_bounds__(256) void k_C(const void* image,
                                           const u16* __restrict__ ST0T, const u16* __restrict__ wt,
                                           u16* __restrict__ PARTB,
                                           const u16* __restrict__ C, const u16* __restrict__ FWF,
                                           const void* fb, float* __restrict__ H){
  __shared__ float sS[130*32];   // 16.6 KB (yinit branch)
  if (blockIdx.x < 1024){
    yinit_body(blockIdx.x, ST0T, wt, PARTB, sS);
  } else {
    bool f32 = probe_f32(image);
    fc_body(blockIdx.x - 1024, f32, C, FWF, fb, H);
  }
}

// ================= k_D: delta (2048 blocks x 2 units) + yred (64) =================
__device__ void delta_body(int obid, int ltid, float* diff, bool f32,
                           const float* __restrict__ H, const u16* __restrict__ wt,
                           const u16* __restrict__ st0t,
                           const int* __restrict__ pos, const void* done,
                           const int* __restrict__ prev, const float* __restrict__ coef,
                           float* __restrict__ dlt8){
  int n = obid >> 2, cq = obid & 3;
  int c0 = cq*130, clen = (cq == 3) ? 127 : 130;
  int b = n & 31;
  int p = pos[n*2]*16 + pos[n*2+1];
  float dn = ldf(f32, done, n);
  float m = 1.f - dn;
  int pv = prev[n];
  float cf = coef[n]*m;
  const float* hc = H + (size_t)n*MAPD + c0;
  for (int c = ltid; c < clen; c += 128){
    float old;
    if (pv >= 0) old = H[(size_t)(pv*32 + b)*MAPD + c0 + c];
    else         old = bfv(st0t[((size_t)p*MAPD + c0 + c)*32 + b]);
    diff[c] = hc[c] - cf*old;
  }
  __syncthreads();
  int half = ltid >> 6, jp = ltid & 63, j0 = jp*2;
  int hbase, hlen;
  if (cq == 3){ hbase = half*64; hlen = half ? 63 : 64; }
  else        { hbase = half*65; hlen = 65; }
  const u16* wp = wt + ((size_t)p*MAPD + c0 + hbase)*128 + j0;
  const float* dptr = diff + hbase;
  float a0 = 0.f, a1 = 0.f;
  int c = 0;
  for (; c + 4 <= hlen; c += 4){
    u32 w0 = *(const u32*)(wp + (size_t)(c+0)*128);
    u32 w1 = *(const u32*)(wp + (size_t)(c+1)*128);
    u32 w2 = *(const u32*)(wp + (size_t)(c+2)*128);
    u32 w3 = *(const u32*)(wp + (size_t)(c+3)*128);
    float d0 = dptr[c], d1 = dptr[c+1], d2 = dptr[c+2], d3 = dptr[c+3];
    a0 += d0*bfv((u16)(w0 & 0xffffu)) + d1*bfv((u16)(w1 & 0xffffu))
        + d2*bfv((u16)(w2 & 0xffffu)) + d3*bfv((u16)(w3 & 0xffffu));
    a1 += d0*bfv((u16)(w0 >> 16)) + d1*bfv((u16)(w1 >> 16))
        + d2*bfv((u16)(w2 >> 16)) + d3*bfv((u16)(w3 >> 16));
  }
  for (; c < hlen; ++c){
    u32 w = *(const u32*)(wp + (size_t)c*128);
    a0 += dptr[c]*bfv((u16)(w & 0xffffu));
    a1 += dptr[c]*bfv((u16)(w >> 16));
  }
  f32x2 st; st[0] = a0; st[1] = a1;
  *(f32x2*)(dlt8 + ((size_t)obid*2 + half)*128 + j0) = st;
}
__global__ __launch_bounds__(256) void k_D(const void* image,
                                           const float* __restrict__ H, const u16* __restrict__ wt,
                                           const u16* __restrict__ st0t,
                                           const int* __restrict__ pos, const void* done,
                                           const int* __restrict__ prev, const float* __restrict__ coef,
                                           float* __restrict__ dlt8,
                                           const u16* __restrict__ PARTB, float* __restrict__ YI){
  __shared__ float diff2[2][132];
  __shared__ float red[256];
  if (blockIdx.x < 2048){
    bool f32 = probe_f32(image);
    int sub = threadIdx.x >> 7;
    int obid = blockIdx.x*2 + sub;
    delta_body(obid, threadIdx.x & 127, diff2[sub], f32, H, wt, st0t, pos, done, prev, coef, dlt8);
  } else {
    int lbid = blockIdx.x - 2048;
    int o = lbid*64 + (threadIdx.x & 63);
    int kq = threadIdx.x >> 6;
    float s = 0.f;
    const u16* pp = PARTB + (size_t)kq*256*4096 + o;
    #pragma unroll 8
    for (int k = 0; k < 256; ++k) s += bfv(pp[(size_t)k*4096]);
    red[threadIdx.x] = s;
    __syncthreads();
    if (threadIdx.x < 64)
      YI[o] = red[threadIdx.x] + red[threadIdx.x+64] + red[threadIdx.x+128] + red[threadIdx.x+192];
  }
}

// ================= k_E: scan+heads (32) + final (2068, 8 elems/thread) =================
__device__ void scan_heads_body(bool f32, const float* __restrict__ yi,
                                const float* __restrict__ dlt8, const void* done,
                                const void* pb1, const void* vb1,
                                const void* pw2, const void* pb2,
                                const void* vw2, const void* vb2, void* out){
  int b = blockIdx.x, j = threadIdx.x;       // j in [0,128)
  int lane = j & 63;
  bool pol = j < 64;
  float y = yi[b*128 + j];
  float bias = pol ? ldf(f32, pb1, j) : ldf(f32, vb1, j-64);
  float w2[5];
  if (pol){
    #pragma unroll
    for (int jj = 0; jj < 5; ++jj) w2[jj] = ldf(f32, pw2, jj*64 + lane);
  } else {
    w2[0] = ldf(f32, vw2, lane);
  }
  for (int t = 0; t < T_; ++t){
    int n = t*32 + b;
    float m = 1.f - ldf(f32, done, n);
    const float* dp = dlt8 + (size_t)n*1024 + j;
    float d = dp[0] + dp[128] + dp[256] + dp[384]
            + dp[512] + dp[640] + dp[768] + dp[896];
    y = m*y + d;
    float th = tanhf(y + bias);
    if (pol){
      float s0 = th*w2[0], s1 = th*w2[1], s2 = th*w2[2], s3 = th*w2[3], s4 = th*w2[4];
      #pragma unroll
      for (int off = 32; off > 0; off >>= 1){
        s0 += __shfl_xor(s0, off, 64);
        s1 += __shfl_xor(s1, off, 64);
        s2 += __shfl_xor(s2, off, 64);
        s3 += __shfl_xor(s3, off, 64);
        s4 += __shfl_xor(s4, off, 64);
      }
      if (lane == 0){
        float sv[5] = {s0,s1,s2,s3,s4};
        #pragma unroll
        for (int jj = 0; jj < 5; ++jj){
          float s = sv[jj] + ldf(f32, pb2, jj);
          if (f32) ((float*)out)[n*5 + jj] = s; else ((u16*)out)[n*5 + jj] = fbf(s);
        }
      }
    } else {
      float s = th*w2[0];
      #pragma unroll
      for (int off = 32; off > 0; off >>= 1) s += __shfl_xor(s, off, 64);
      if (lane == 0){
        s += ldf(f32, vb2, 0);
        if (f32) ((float*)out)[5120 + n] = s; else ((u16*)out)[5120 + n] = fbf(s);
      }
    }
  }
}
__global__ __launch_bounds__(256) void k_E(const void* image,
                                           const float* __restrict__ yi, const float* __restrict__ dlt8,
                                           const void* done, const void* pb1, const void* vb1,
                                           const void* pw2, const void* pb2,
                                           const void* vw2, const void* vb2,
                                           const float* __restrict__ H, const void* st0,
                                           const int* __restrict__ lastw, const float* __restrict__ lastc,
                                           void* out){
  bool f32 = probe_f32(image);
  if (blockIdx.x < 32){
    if (threadIdx.x >= 128) return;
    scan_heads_body(f32, yi, dlt8, done, pb1, vb1, pw2, pb2, vw2, vb2, out);
  } else {
    // final_state: 8 elements/thread. FLATD%8==0 and 256%8==0 -> one thread's
    // 8 consecutive i share b and c; p0..p0+7 consecutive.
    size_t i0 = (size_t)(blockIdx.x - 32)*2048 + (size_t)threadIdx.x*8;
    int b = (int)(i0 / FLATD);
    int r = (int)(i0 - (size_t)b*FLATD);
    int c = r >> 8, p0 = r & 255;
    int4 lwa = *(const int4*)(lastw + b*256 + p0);
    int4 lwb = *(const int4*)(lastw + b*256 + p0 + 4);
    float4 lca = *(const float4*)(lastc + b*256 + p0);
    float4 lcb = *(const float4*)(lastc + b*256 + p0 + 4);
    int   lw[8] = {lwa.x,lwa.y,lwa.z,lwa.w,lwb.x,lwb.y,lwb.z,lwb.w};
    float lc[8] = {lca.x,lca.y,lca.z,lca.w,lcb.x,lcb.y,lcb.z,lcb.w};
    float v[8];
    #pragma unroll
    for (int k = 0; k < 8; ++k){
      float x;
      if (lw[k] >= 0) x = H[(size_t)(lw[k]*32 + b)*MAPD + c];
      else            x = ldf(f32, st0, i0 + k);
      v[k] = x*lc[k];
    }
    if (f32){
      float4 o0 = {v[0],v[1],v[2],v[3]}, o1 = {v[4],v[5],v[6],v[7]};
      float* op = (float*)out + 6144 + i0;
      *(float4*)op = o0; *(float4*)(op+4) = o1;
    } else {
      ushort4 o0, o1;
      o0.x=fbf(v[0]); o0.y=fbf(v[1]); o0.z=fbf(v[2]); o0.w=fbf(v[3]);
      o1.x=fbf(v[4]); o1.y=fbf(v[5]); o1.z=fbf(v[6]); o1.w=fbf(v[7]);
      u16* op = (u16*)out + 6144 + i0;
      *(ushort4*)op = o0; *(ushort4*)(op+4) = o1;
    }
  }
}

extern "C" void kernel_launch(void* const* d_in, const int* in_sizes, int n_in,
                              void* d_out, int out_size, void* d_ws, size_t ws_size,
                              hipStream_t stream) {
  (void)in_sizes; (void)n_in; (void)out_size; (void)ws_size;
  const void* image = d_in[0];
  const int*  lact  = (const int*)d_in[1];
  const int*  pos   = (const int*)d_in[2];
  const void* done  = d_in[3];
  const void* st0   = d_in[4];
  const void* c1w = d_in[5];  const void* c1b = d_in[6];
  const void* c2w = d_in[7];  const void* c2b = d_in[8];
  const void* c3w = d_in[9];  const void* c3b = d_in[10];
  const void* fcw = d_in[11]; const void* fcb = d_in[12];
  const void* pw1 = d_in[13]; const void* pb1 = d_in[14];
  const void* pw2 = d_in[15]; const void* pb2 = d_in[16];
  const void* vw1 = d_in[17]; const void* vb1 = d_in[18];
  const void* vw2 = d_in[19]; const void* vb2 = d_in[20];
  char* ws = (char*)d_ws;

  // workspace (~60.5 MB). No live overlays.
  u16*   WT    = (u16*)  (ws + 0);           // 33,882,112
  float* H     = (float*)(ws + 33882368);    // 2,117,632
  float* YI    = (float*)(ws + 36000256);    // 16,384
  u16*   PARTB = (u16*)  (ws + 36016640);    // 8,388,608
  int*   PREV  = (int*)  (ws + 44405248);
  float* COEF  = (float*)(ws + 44409344);
  int*   LASTW = (int*)  (ws + 44413440);
  float* LASTC = (float*)(ws + 44446208);
  u16*   W1F   = (u16*)  (ws + 44479232);    // 12,288
  u16*   W2F   = (u16*)  (ws + 44491520);    // 65,536
  u16*   W3F   = (u16*)  (ws + 44557056);    // 73,728
  u16*   FWF   = (u16*)  (ws + 44630784);    // 1,048,576
  u16*   ST0T  = (u16*)  (ws + 45679360);    // 8,470,528 -> 54,149,888
  u16*   C     = (u16*)  (ws + 54149888);    // 2,097,152 -> 56,247,040
  float* DLT8  = (float*)(ws + 56247040);    // 4,194,304 -> 60,441,344

  k_A      <<<1754, 256, 0, stream>>>(image, pw1, vw1, WT, c1w, c2w, c3w, fcw, st0,
                                      W1F, W2F, W3F, FWF, ST0T,
                                      pos, done, lact, PREV, COEF, H, LASTW, LASTC);
  k_conv123<<<1024, 256, 0, stream>>>(image, W1F, c1b, W2F, c2b, W3F, c3b, C);
  k_C      <<<1536, 256, 0, stream>>>(image, ST0T, WT, PARTB, C, FWF, fcb, H);
  k_D      <<<2112, 256, 0, stream>>>(image, H, WT, ST0T, pos, done, PREV, COEF, DLT8, PARTB, YI);
  k_E      <<<2100, 256, 0, stream>>>(image, YI, DLT8, done, pb1, vb1, pw2, pb2, vw2, vb2,
                                      H, st0, LASTW, LASTC, d_out);
}

// Round 9
// 322.488 us; speedup vs baseline: 1.0291x; 1.0291x over previous
//
#include <hip/hip_runtime.h>

#define T_ 32
#define B_ 32
#define MAPD 517
#define P_ 256
#define FLATD (MAPD*P_)   // 132352
#define TBN (T_*B_)       // 1024

typedef unsigned short u16;
typedef unsigned int u32;
typedef __attribute__((ext_vector_type(4))) short short4v;
typedef __attribute__((ext_vector_type(8))) short short8v;
typedef __attribute__((ext_vector_type(4))) float f32x4;
typedef __attribute__((ext_vector_type(2))) float f32x2;
typedef __attribute__((ext_vector_type(4))) u32 u32x4;

__device__ __forceinline__ float bfv(u16 u){ u32 x = ((u32)u)<<16; return __uint_as_float(x); }
__device__ __forceinline__ u16 fbf(float f){
  u32 x = __float_as_uint(f);
  return (u16)((x + 0x7fffu + ((x>>16)&1u))>>16);
}
template<bool F32> __device__ __forceinline__ float ld(const void* p, size_t i){
  if constexpr (F32) return ((const float*)p)[i];
  else               return bfv(((const u16*)p)[i]);
}
__device__ __forceinline__ float ldf(bool f32, const void* p, size_t i){
  return f32 ? ((const float*)p)[i] : bfv(((const u16*)p)[i]);
}

// ---- inline dtype probe: per-wave, no barrier ----
__device__ __forceinline__ bool probe_f32(const void* img){
  int lane = threadIdx.x & 63;
  ushort4 v = ((const ushort4*)img)[lane];      // lanes cover first 256 u16
  int c = (v.x <= 0x4380u) + (v.y <= 0x4380u) + (v.z <= 0x4380u) + (v.w <= 0x4380u);
  #pragma unroll
  for (int off = 32; off > 0; off >>= 1) c += __shfl_xor(c, off, 64);
  return c < 240;
}

// ================= k_A: wt-transpose (1034) + prep (684) + meta (36) =================
template<bool F32> __device__ void wt_body(int lbid, const void* pw1, const void* vw1,
                                           u16* wt, u32* tile){
  int c  = lbid >> 1;
  int ph = lbid & 1;
  for (int it = 0; it < 4; ++it){
    int idx = it*256 + threadIdx.x;        // [0,1024)
    int jp = idx >> 4, pg = idx & 15;      // jp: 64 j-pairs, pg: 16 pp-groups of 8
    int j0 = jp*2;
    const void* w = (j0 < 64) ? pw1 : vw1;
    int jj0 = (j0 < 64) ? j0 : j0-64;
    size_t base0 = (size_t)jj0*FLATD + c*P_ + ph*128 + pg*8;
    size_t base1 = base0 + FLATD;
    u16 a[8], b[8];
    if constexpr (F32){
      const float* f = (const float*)w;
      float4 a0 = *(const float4*)(f + base0), a1 = *(const float4*)(f + base0 + 4);
      float4 b0 = *(const float4*)(f + base1), b1 = *(const float4*)(f + base1 + 4);
      a[0]=fbf(a0.x); a[1]=fbf(a0.y); a[2]=fbf(a0.z); a[3]=fbf(a0.w);
      a[4]=fbf(a1.x); a[5]=fbf(a1.y); a[6]=fbf(a1.z); a[7]=fbf(a1.w);
      b[0]=fbf(b0.x); b[1]=fbf(b0.y); b[2]=fbf(b0.z); b[3]=fbf(b0.w);
      b[4]=fbf(b1.x); b[5]=fbf(b1.y); b[6]=fbf(b1.z); b[7]=fbf(b1.w);
    } else {
      short8v va = *(const short8v*)((const u16*)w + base0);
      short8v vb = *(const short8v*)((const u16*)w + base1);
      #pragma unroll
      for (int k = 0; k < 8; ++k){ a[k] = (u16)va[k]; b[k] = (u16)vb[k]; }
    }
    int slot = (jp >> 2) ^ pg;
    int sub  = jp & 3;
    #pragma unroll
    for (int k = 0; k < 8; ++k){
      int pp = pg*8 + k;
      tile[pp*64 + slot*4 + sub] = (u32)a[k] | ((u32)b[k] << 16);
    }
  }
  __syncthreads();
  for (int it = 0; it < 8; ++it){
    int idx = it*256 + threadIdx.x;        // [0,2048)
    int pp = idx >> 4, jb = idx & 15;
    int slot = jb ^ ((pp >> 3) & 15);
    u32x4 v = *(const u32x4*)(tile + pp*64 + slot*4);
    int p = ph*128 + pp;
    *(u32x4*)(wt + ((size_t)p*MAPD + c)*128 + jb*8) = v;
  }
}

__device__ void prep_body(bool f32, int bid, const void* c1w, const void* c2w, const void* c3w,
                          const void* fcw, const void* st0,
                          u16* W1F, u16* W2F, u16* W3F, u16* FWF, u16* ST0T, char* smem_){
  int tid = threadIdx.x;
  if (bid < 24){
    int idx = bid*256 + tid;                   // 6144
    int j = idx & 7, l = (idx>>3) & 63, t = idx>>9;
    int nt = t/6, s = t - nt*6;
    int oc = nt*16 + (l&15);
    int kk = 8*(4*s + (l>>4)) + j;
    float v = ldf(f32, c1w, oc*192+kk);
    W1F[idx] = fbf(v);
  } else if (bid < 152){
    int idx = (bid-24)*256 + tid;              // 32768
    int j = idx & 7, l = (idx>>3) & 63, s = (idx>>9) & 15, nt = idx>>13;
    int oc = nt*16 + (l&15);
    int cin = (l>>4)*8 + j;
    int src = oc*512 + cin*16 + (s>>2)*4 + (s&3);
    W2F[idx] = fbf(ldf(f32, c2w, src));
  } else if (bid < 296){
    int idx = (bid-152)*256 + tid;             // 36864
    int j = idx & 7, l = (idx>>3) & 63, t = idx>>9;   // t = nt*18+s
    int nt = t/18, s = t - nt*18;
    int oc = nt*16 + (l&15);
    int c = (s&1)*32 + (l>>4)*8 + j;
    int src = oc*576 + c*9 + (s>>1);
    W3F[idx] = fbf(ldf(f32, c3w, src));
  } else if (bid < 424){
    // FWF: MFMA B-fragments of fc_w for fc GEMM.
    int b = bid - 296;                          // 128 blocks x 4096 elems
    for (int it = 0; it < 16; ++it){
      int idx = (b*16 + it)*256 + tid;          // 524288 total
      int j = idx & 7, l = (idx>>3) & 63, frag = idx >> 9;
      int nt = frag >> 5, kt = frag & 31;
      int kc = kt*32 + ((l>>4)<<3) + j;
      int kr = (kc & 63)*16 + (kc >> 6);
      int o  = nt*16 + (l & 15);
      FWF[idx] = fbf(ldf(f32, fcw, (size_t)o*1024 + kr));
    }
  } else {
    // ST0T[p][c][b] transpose — vectorized both sides, pad-36 LDS, rotated write order.
    u16* tile = (u16*)smem_;                   // [ci<4][pl<64] stride 36 u16 + b
    int b0 = bid - 424;                        // 260 blocks
    int c0 = (b0 >> 2)*8, p0 = (b0 & 3)*64;
    for (int half = 0; half < 2; ++half){
      int ch = c0 + half*4;
      for (int it = 0; it < 4; ++it){
        int idx = it*256 + tid;                // [0,1024)
        int pg = idx & 7, b = (idx>>3) & 31, ci = idx >> 8;   // ci 0..3
        int c = ch + ci;
        u16 v[8];
        if (c < MAPD){
          size_t src = ((size_t)b*MAPD + c)*256 + p0 + pg*8;
          if (f32){
            const float* f = (const float*)st0;
            float4 x0 = *(const float4*)(f + src), x1 = *(const float4*)(f + src + 4);
            v[0]=fbf(x0.x); v[1]=fbf(x0.y); v[2]=fbf(x0.z); v[3]=fbf(x0.w);
            v[4]=fbf(x1.x); v[5]=fbf(x1.y); v[6]=fbf(x1.z); v[7]=fbf(x1.w);
          } else {
            short8v x = *(const short8v*)((const u16*)st0 + src);
            #pragma unroll
            for (int k = 0; k < 8; ++k) v[k] = (u16)x[k];
          }
        } else {
          #pragma unroll
          for (int k = 0; k < 8; ++k) v[k] = 0;
        }
        #pragma unroll
        for (int kk = 0; kk < 8; ++kk){
          int k2 = (kk + pg) & 7;
          tile[ci*2304 + (pg*8 + k2)*36 + b] = v[k2];
        }
      }
      __syncthreads();
      for (int it = 0; it < 8; ++it){
        int idx = it*256 + tid;                // [0,2048)
        int bq = idx & 7, pl = (idx>>3) & 63, ci = idx >> 9;  // ci 0..3
        int c = ch + ci;
        if (c < MAPD){
          ushort4 v = *(const ushort4*)(tile + ci*2304 + pl*36 + bq*4);
          *(ushort4*)(ST0T + ((size_t)(p0+pl)*MAPD + c)*32 + bq*4) = v;
        }
      }
      __syncthreads();
    }
  }
}

__device__ void meta_body(bool f32, int bid, const int* pos, const void* done, const int* lact,
                          int* prev, float* coef, float* H, int* lastw, float* lastc){
  if (bid < 4){
    int i = bid*256 + threadIdx.x;
    int t = i >> 5, b = i & 31;
    int p = pos[i*2]*16 + pos[i*2+1];
    int pv = -1;
    for (int s = t-1; s >= 0; --s){
      int n = s*32 + b;
      if (pos[n*2]*16 + pos[n*2+1] == p){ pv = s; break; }
    }
    float cf = 1.f;
    for (int s = (pv<0?0:pv+1); s <= t-1; ++s)
      cf *= (1.f - ldf(f32, done, s*32+b));
    prev[i] = pv; coef[i] = cf;
    int la = lact[i];
    #pragma unroll
    for (int a = 0; a < 5; ++a) H[(size_t)i*MAPD + 512 + a] = (la == a) ? 1.f : 0.f;
  } else {
    int i = (bid-4)*256 + threadIdx.x;
    int b = i >> 8, p = i & 255;
    int lw = -1;
    for (int s = T_-1; s >= 0; --s){
      int n = s*32 + b;
      if (pos[n*2]*16 + pos[n*2+1] == p){ lw = s; break; }
    }
    float cf = 1.f;
    for (int s = (lw<0?0:lw+1); s < T_; ++s)
      cf *= (1.f - ldf(f32, done, s*32+b));
    lastw[i] = lw; lastc[i] = cf;
  }
}

__global__ __launch_bounds__(256) void k_A(const void* image,
                                           const void* pw1, const void* vw1, u16* wt,
                                           const void* c1w, const void* c2w, const void* c3w,
                                           const void* fcw, const void* st0,
                                           u16* W1F, u16* W2F, u16* W3F, u16* FWF, u16* ST0T,
                                           const int* pos, const void* done, const int* lact,
                                           int* prev, float* coef, float* H, int* lastw, float* lastc){
  __shared__ __align__(16) char smem_[32768];
  bool f32 = probe_f32(image);
  int bid = blockIdx.x;
  if (bid < 1034){
    if (f32) wt_body<true>(bid, pw1, vw1, wt, (u32*)smem_);
    else     wt_body<false>(bid, pw1, vw1, wt, (u32*)smem_);
  } else if (bid < 1718){
    prep_body(f32, bid-1034, c1w, c2w, c3w, fcw, st0, W1F, W2F, W3F, FWF, ST0T, smem_);
  } else {
    meta_body(f32, bid-1718, pos, done, lact, prev, coef, H, lastw, lastc);
  }
}

// ================= k_conv123: fused convs =================
__global__ __launch_bounds__(256) void k_conv123(const void* img,
                                                 const u16* __restrict__ W1F, const void* b1,
                                                 const u16* __restrict__ W2F, const void* b2,
                                                 const u16* __restrict__ W3F, const void* b3,
                                                 u16* __restrict__ out){
  __shared__ __align__(16) u16 smem[19488];
  u16* sImg = smem;            // 12288 u16
  u16* sA   = smem + 12288;    // 7200 u16
  u16* sBv  = smem;            // 2304 u16, overlays sImg after conv1
  bool f32 = probe_f32(img);
  int n = blockIdx.x, tid = threadIdx.x;
  if (f32){
    const float4* ip = (const float4*)((const float*)img + (size_t)n*12288);
    for (int i = tid; i < 3072; i += 256){
      float4 v = ip[i];
      ushort4 u; u.x = fbf(v.x); u.y = fbf(v.y); u.z = fbf(v.z); u.w = fbf(v.w);
      int L = i*4;
      int addr = (L & ~63) | (((L & 63) + (((L >> 6) & 3) << 4)) & 63);
      *(ushort4*)(sImg + addr) = u;
    }
  } else {
    const ushort4* ip = (const ushort4*)((const u16*)img + (size_t)n*12288);
    for (int i = tid; i < 3072; i += 256){
      ushort4 u = ip[i];
      int L = i*4;
      int addr = (L & ~63) | (((L & 63) + (((L >> 6) & 3) << 4)) & 63);
      *(ushort4*)(sImg + addr) = u;
    }
  }
  int wv = tid >> 6, lane = tid & 63;
  int mi = lane & 15, q = lane >> 4;

  short8v bfr1[2][6];
  #pragma unroll
  for (int nt = 0; nt < 2; ++nt)
    #pragma unroll
    for (int s = 0; s < 6; ++s)
      bfr1[nt][s] = ((const short8v*)W1F)[(nt*6+s)*64 + lane];
  float b1v[2];
  #pragma unroll
  for (int nt = 0; nt < 2; ++nt)
    b1v[nt] = ldf(f32, b1, nt*16+mi);
  __syncthreads();

  {
    f32x4 acc[4][2];
    #pragma unroll
    for (int mt = 0; mt < 4; ++mt)
      #pragma unroll
      for (int nt = 0; nt < 2; ++nt)
        acc[mt][nt] = (f32x4){0.f,0.f,0.f,0.f};
    int base[4];
    #pragma unroll
    for (int mt = 0; mt < 4; ++mt){
      int m = (wv*4+mt)*16 + mi;
      int mc = m < 225 ? m : 224;
      int oy = mc/15, ox = mc - oy*15;
      base[mt] = oy*256 + ox*4;
    }
    for (int s = 0; s < 6; ++s){
      int cky = 4*s + q;
      int off = (cky >> 3)*4096 + (cky & 7)*64;
      #pragma unroll
      for (int mt = 0; mt < 4; ++mt){
        int Lb = base[mt] + off;
        const u16* rp = sImg + (Lb & ~63);
        int x0 = Lb & 63;
        int rot = ((Lb >> 6) & 3) << 4;
        short4v lo = *(const short4v*)(rp + ((x0 + rot) & 63));
        short4v hi = *(const short4v*)(rp + ((x0 + 4 + rot) & 63));
        short8v a = __builtin_shufflevector(lo, hi, 0,1,2,3,4,5,6,7);
        acc[mt][0] = __builtin_amdgcn_mfma_f32_16x16x32_bf16(a, bfr1[0][s], acc[mt][0], 0,0,0);
        acc[mt][1] = __builtin_amdgcn_mfma_f32_16x16x32_bf16(a, bfr1[1][s], acc[mt][1], 0,0,0);
      }
    }
    __syncthreads();   // sImg reads done before sBv (alias) writes in conv2
    #pragma unroll
    for (int mt = 0; mt < 4; ++mt){
      int mrow0 = (wv*4+mt)*16 + q*4;
      #pragma unroll
      for (int nt = 0; nt < 2; ++nt){
        int oc = nt*16 + mi;
        #pragma unroll
        for (int r = 0; r < 4; ++r){
          int m = mrow0 + r;
          if (m < 225){
            int g = ((oc >> 3) ^ ((m >> 1) & 3)) << 3;
            sA[m*32 + g + (oc & 7)] = fbf(fmaxf(acc[mt][nt][r] + b1v[nt], 0.f));
          }
        }
      }
    }
  }
  __syncthreads();

  {
    short8v bfr2[16];
    #pragma unroll
    for (int s = 0; s < 16; ++s)
      bfr2[s] = ((const short8v*)W2F)[(wv*16+s)*64 + lane];
    int oc = wv*16 + mi;
    float bv = ldf(f32, b2, oc);
    f32x4 acc[3];
    #pragma unroll
    for (int mt = 0; mt < 3; ++mt) acc[mt] = (f32x4){0.f,0.f,0.f,0.f};
    int pixb[3];
    #pragma unroll
    for (int mt = 0; mt < 3; ++mt){
      int m = mt*16 + mi; if (m > 35) m = 35;
      int oy = m/6, ox = m - oy*6;
      pixb[mt] = oy*30 + ox*2;
    }
    #pragma unroll
    for (int s = 0; s < 16; ++s){
      int dp = (s>>2)*15 + (s&3);
      #pragma unroll
      for (int mt = 0; mt < 3; ++mt){
        int pix = pixb[mt] + dp;
        int g = (q ^ ((pix >> 1) & 3)) << 3;
        short8v a = *(const short8v*)(sA + pix*32 + g);
        acc[mt] = __builtin_amdgcn_mfma_f32_16x16x32_bf16(a, bfr2[s], acc[mt], 0,0,0);
      }
    }
    __syncthreads();
    #pragma unroll
    for (int mt = 0; mt < 3; ++mt)
      #pragma unroll
      for (int r = 0; r < 4; ++r){
        int m = mt*16 + q*4 + r;
        if (m < 36){
          int g = ((oc >> 3) ^ (m & 7)) << 3;
          sBv[m*64 + g + (oc & 7)] = fbf(fmaxf(acc[mt][r] + bv, 0.f));
        }
      }
  }
  __syncthreads();

  {
    int oy = mi >> 2, ox = mi & 3;
    int oc = wv*16 + mi;
    float bv = ldf(f32, b3, oc);
    short8v bfr3[18];
    #pragma unroll
    for (int s = 0; s < 18; ++s)
      bfr3[s] = ((const short8v*)W3F)[(wv*18+s)*64 + lane];
    f32x4 acc = (f32x4){0.f,0.f,0.f,0.f};
    #pragma unroll
    for (int s = 0; s < 18; ++s){
      int pair = s >> 1, ky = pair/3, kx = pair - ky*3;
      int pix = (oy+ky)*6 + ox+kx;
      int g = ((((s & 1) << 2) | q) ^ (pix & 7)) << 3;
      short8v a = *(const short8v*)(sBv + pix*64 + g);
      acc = __builtin_amdgcn_mfma_f32_16x16x32_bf16(a, bfr3[s], acc, 0,0,0);
    }
    u16* ob = out + (size_t)n*1024;
    #pragma unroll
    for (int r = 0; r < 4; ++r)
      ob[(q*4+r)*64 + oc] = fbf(fmaxf(acc[r] + bv, 0.f));
  }
}

// ================= k_C: yinit (1024) + fc (512) =================
template<int CLEN>
__device__ __forceinline__ void yloop(const u16* __restrict__ wp, const float* __restrict__ sSb,
                                      float (&acc)[8][2]){
  #pragma unroll 10
  for (int c = 0; c < CLEN; ++c){
    u32 w = *(const u32*)(wp + (size_t)c*128);
    float w0 = bfv((u16)(w & 0xffffu)), w1 = bfv((u16)(w >> 16));
    const float4* s4 = (const float4*)(sSb + c*32);
    float4 sa = s4[0], sb = s4[1];
    float sv[8] = {sa.x,sa.y,sa.z,sa.w,sb.x,sb.y,sb.z,sb.w};
    #pragma unroll
    for (int bb = 0; bb < 8; ++bb){
      acc[bb][0] += sv[bb]*w0;
      acc[bb][1] += sv[bb]*w1;
    }
  }
}
__device__ void yinit_body(int lbid, const u16* __restrict__ ST0T, const u16* __restrict__ wt,
                           u16* __restrict__ PARTB, float* sS){
  int p = lbid >> 2, cq = lbid & 3;
  int c0 = cq*130;
  int clen = (cq == 3) ? 127 : 130;
  const ushort4* ssrc = (const ushort4*)(ST0T + ((size_t)p*MAPD + c0)*32);
  int n4 = clen*8;
  for (int i = threadIdx.x; i < n4; i += 256){
    ushort4 u = ssrc[i];
    float4 f; f.x = bfv(u.x); f.y = bfv(u.y); f.z = bfv(u.z); f.w = bfv(u.w);
    *(float4*)(sS + i*4) = f;
  }
  __syncthreads();
  int jg = threadIdx.x & 63, bg = threadIdx.x >> 6;
  int j0 = jg*2, b0 = bg*8;
  const u16* wp = wt + ((size_t)p*MAPD + c0)*128 + j0;
  float acc[8][2] = {};
  if (cq < 3) yloop<130>(wp, sS + b0, acc);
  else        yloop<127>(wp, sS + b0, acc);
  u32* op = (u32*)(PARTB + (size_t)lbid*4096);
  #pragma unroll
  for (int bb = 0; bb < 8; ++bb){
    u32 pk = (u32)fbf(acc[bb][0]) | ((u32)fbf(acc[bb][1]) << 16);
    op[((b0+bb)*128 + j0) >> 1] = pk;
  }
}
__device__ void fc_body(int lbid, bool f32, const u16* __restrict__ C, const u16* __restrict__ FWF,
                        const void* fb, float* __restrict__ H){
  int wv = threadIdx.x >> 6, lane = threadIdx.x & 63;
  int mi = lane & 15, q = lane >> 4;
  int mt = lbid >> 3;               // 0..63
  int nt = (lbid & 7)*4 + wv;       // 0..31
  const u16* ap = C + (size_t)(mt*16 + mi)*1024 + q*8;
  const short8v* bp = (const short8v*)FWF + (size_t)nt*32*64 + lane;
  f32x4 acc0 = (f32x4){0.f,0.f,0.f,0.f};
  f32x4 acc1 = (f32x4){0.f,0.f,0.f,0.f};
  #pragma unroll
  for (int kt = 0; kt < 32; kt += 2){
    short8v a0 = *(const short8v*)(ap + kt*32);
    short8v b0 = bp[kt*64];
    short8v a1 = *(const short8v*)(ap + (kt+1)*32);
    short8v b1 = bp[(kt+1)*64];
    acc0 = __builtin_amdgcn_mfma_f32_16x16x32_bf16(a0, b0, acc0, 0,0,0);
    acc1 = __builtin_amdgcn_mfma_f32_16x16x32_bf16(a1, b1, acc1, 0,0,0);
  }
  int o = nt*16 + mi;
  float bv = ldf(f32, fb, o);
  #pragma unroll
  for (int r = 0; r < 4; ++r){
    int m = mt*16 + q*4 + r;
    H[(size_t)m*MAPD + o] = fmaxf(acc0[r] + acc1[r] + bv, 0.f);
  }
}
__global__ __launch_bounds__(256) void k_C(const void* image,
                                           const u16* __restrict__ ST0T, const u16* __restrict__ wt,
                                           u16* __restrict__ PARTB,
                                           const u16* __restrict__ C, const u16* __restrict__ FWF,
                                           const void* fb, float* __restrict__ H){
  __shared__ float sS[130*32];   // 16.6 KB (yinit branch)
  if (blockIdx.x < 1024){
    yinit_body(blockIdx.x, ST0T, wt, PARTB, sS);
  } else {
    bool f32 = probe_f32(image);
    fc_body(blockIdx.x - 1024, f32, C, FWF, fb, H);
  }
}

// ================= k_D: delta (2048 blocks x 2 units) + yred (64) =================
__device__ void delta_body(int obid, int ltid, float* diff, bool f32,
                           const float* __restrict__ H, const u16* __restrict__ wt,
                           const u16* __restrict__ st0t,
                           const int* __restrict__ pos, const void* done,
                           const int* __restrict__ prev, const float* __restrict__ coef,
                           float* __restrict__ dlt8){
  int n = obid >> 2, cq = obid & 3;
  int c0 = cq*130, clen = (cq == 3) ? 127 : 130;
  int b = n & 31;
  int p = pos[n*2]*16 + pos[n*2+1];
  float dn = ldf(f32, done, n);
  float m = 1.f - dn;
  int pv = prev[n];
  float cf = coef[n]*m;
  const float* hc = H + (size_t)n*MAPD + c0;
  for (int c = ltid; c < clen; c += 128){
    float old;
    if (pv >= 0) old = H[(size_t)(pv*32 + b)*MAPD + c0 + c];
    else         old = bfv(st0t[((size_t)p*MAPD + c0 + c)*32 + b]);
    diff[c] = hc[c] - cf*old;
  }
  __syncthreads();
  int half = ltid >> 6, jp = ltid & 63, j0 = jp*2;
  int hbase, hlen;
  if (cq == 3){ hbase = half*64; hlen = half ? 63 : 64; }
  else        { hbase = half*65; hlen = 65; }
  const u16* wp = wt + ((size_t)p*MAPD + c0 + hbase)*128 + j0;
  const float* dptr = diff + hbase;
  float a0 = 0.f, a1 = 0.f;
  int c = 0;
  for (; c + 4 <= hlen; c += 4){
    u32 w0 = *(const u32*)(wp + (size_t)(c+0)*128);
    u32 w1 = *(const u32*)(wp + (size_t)(c+1)*128);
    u32 w2 = *(const u32*)(wp + (size_t)(c+2)*128);
    u32 w3 = *(const u32*)(wp + (size_t)(c+3)*128);
    float d0 = dptr[c], d1 = dptr[c+1], d2 = dptr[c+2], d3 = dptr[c+3];
    a0 += d0*bfv((u16)(w0 & 0xffffu)) + d1*bfv((u16)(w1 & 0xffffu))
        + d2*bfv((u16)(w2 & 0xffffu)) + d3*bfv((u16)(w3 & 0xffffu));
    a1 += d0*bfv((u16)(w0 >> 16)) + d1*bfv((u16)(w1 >> 16))
        + d2*bfv((u16)(w2 >> 16)) + d3*bfv((u16)(w3 >> 16));
  }
  for (; c < hlen; ++c){
    u32 w = *(const u32*)(wp + (size_t)c*128);
    a0 += dptr[c]*bfv((u16)(w & 0xffffu));
    a1 += dptr[c]*bfv((u16)(w >> 16));
  }
  f32x2 st; st[0] = a0; st[1] = a1;
  *(f32x2*)(dlt8 + ((size_t)obid*2 + half)*128 + j0) = st;
}
__global__ __launch_bounds__(256) void k_D(const void* image,
                                           const float* __restrict__ H, const u16* __restrict__ wt,
                                           const u16* __restrict__ st0t,
                                           const int* __restrict__ pos, const void* done,
                                           const int* __restrict__ prev, const float* __restrict__ coef,
                                           float* __restrict__ dlt8,
                                           const u16* __restrict__ PARTB, float* __restrict__ YI){
  __shared__ float diff2[2][132];
  __shared__ float red[256];
  if (blockIdx.x < 2048){
    bool f32 = probe_f32(image);
    int sub = threadIdx.x >> 7;
    int obid = blockIdx.x*2 + sub;
    delta_body(obid, threadIdx.x & 127, diff2[sub], f32, H, wt, st0t, pos, done, prev, coef, dlt8);
  } else {
    int lbid = blockIdx.x - 2048;
    int o = lbid*64 + (threadIdx.x & 63);
    int kq = threadIdx.x >> 6;
    float s = 0.f;
    const u16* pp = PARTB + (size_t)kq*256*4096 + o;
    #pragma unroll 8
    for (int k = 0; k < 256; ++k) s += bfv(pp[(size_t)k*4096]);
    red[threadIdx.x] = s;
    __syncthreads();
    if (threadIdx.x < 64)
      YI[o] = red[threadIdx.x] + red[threadIdx.x+64] + red[threadIdx.x+128] + red[threadIdx.x+192];
  }
}

// ================= k_E: scan+heads (32, LDS-prefetched) + final (2068, vector st0) ========
__device__ void scan_heads_body(bool f32, const float* __restrict__ yi,
                                const float* __restrict__ dlt8, const void* done,
                                const void* pb1, const void* vb1,
                                const void* pw2, const void* pb2,
                                const void* vw2, const void* vb2, void* out,
                                float* sd, float* sm){
  int b = blockIdx.x;
  // Phase 1 (all 256 threads): sum the 8 DLT8 partials for every (t,j) into LDS.
  // All loads independent -> fully pipelined; removes serial-loop memory stalls.
  for (int it = 0; it < 16; ++it){
    int idx = it*256 + threadIdx.x;          // 4096 = 32t x 128j
    int t = idx >> 7, j = idx & 127;
    const float* dp = dlt8 + (size_t)(t*32 + b)*1024 + j;
    sd[idx] = dp[0] + dp[128] + dp[256] + dp[384]
            + dp[512] + dp[640] + dp[768] + dp[896];
  }
  if (threadIdx.x < 32) sm[threadIdx.x] = 1.f - ldf(f32, done, threadIdx.x*32 + b);
  __syncthreads();
  if (threadIdx.x >= 128) return;
  // Phase 2 (128 threads): serial recurrence + heads, all operands in LDS/regs.
  int j = threadIdx.x;
  int lane = j & 63;
  bool pol = j < 64;
  float y = yi[b*128 + j];
  float bias = pol ? ldf(f32, pb1, j) : ldf(f32, vb1, j-64);
  float w2[5];
  if (pol){
    #pragma unroll
    for (int jj = 0; jj < 5; ++jj) w2[jj] = ldf(f32, pw2, jj*64 + lane);
  } else {
    w2[0] = ldf(f32, vw2, lane);
  }
  for (int t = 0; t < T_; ++t){
    int n = t*32 + b;
    y = sm[t]*y + sd[t*128 + j];
    float th = tanhf(y + bias);
    if (pol){
      float s0 = th*w2[0], s1 = th*w2[1], s2 = th*w2[2], s3 = th*w2[3], s4 = th*w2[4];
      #pragma unroll
      for (int off = 32; off > 0; off >>= 1){
        s0 += __shfl_xor(s0, off, 64);
        s1 += __shfl_xor(s1, off, 64);
        s2 += __shfl_xor(s2, off, 64);
        s3 += __shfl_xor(s3, off, 64);
        s4 += __shfl_xor(s4, off, 64);
      }
      if (lane == 0){
        float sv[5] = {s0,s1,s2,s3,s4};
        #pragma unroll
        for (int jj = 0; jj < 5; ++jj){
          float s = sv[jj] + ldf(f32, pb2, jj);
          if (f32) ((float*)out)[n*5 + jj] = s; else ((u16*)out)[n*5 + jj] = fbf(s);
        }
      }
    } else {
      float s = th*w2[0];
      #pragma unroll
      for (int off = 32; off > 0; off >>= 1) s += __shfl_xor(s, off, 64);
      if (lane == 0){
        s += ldf(f32, vb2, 0);
        if (f32) ((float*)out)[5120 + n] = s; else ((u16*)out)[5120 + n] = fbf(s);
      }
    }
  }
}
__global__ __launch_bounds__(256) void k_E(const void* image,
                                           const float* __restrict__ yi, const float* __restrict__ dlt8,
                                           const void* done, const void* pb1, const void* vb1,
                                           const void* pw2, const void* pb2,
                                           const void* vw2, const void* vb2,
                                           const float* __restrict__ H, const void* st0,
                                           const int* __restrict__ lastw, const float* __restrict__ lastc,
                                           void* out){
  __shared__ float sd[32*128];   // 16 KB (scan branch; 8 blocks/CU still hit 32-wave cap)
  __shared__ float sm[32];
  bool f32 = probe_f32(image);
  if (blockIdx.x < 32){
    scan_heads_body(f32, yi, dlt8, done, pb1, vb1, pw2, pb2, vw2, vb2, out, sd, sm);
  } else {
    // final_state: 8 elems/thread. Unconditional VECTOR st0 load (coalesced 16B),
    // sparse H-gather overwrite only where lw>=0 (~12% of elements).
    size_t i0 = (size_t)(blockIdx.x - 32)*2048 + (size_t)threadIdx.x*8;
    int b = (int)(i0 / FLATD);
    int r = (int)(i0 - (size_t)b*FLATD);
    int c = r >> 8, p0 = r & 255;
    int4 lwa = *(const int4*)(lastw + b*256 + p0);
    int4 lwb = *(const int4*)(lastw + b*256 + p0 + 4);
    float4 lca = *(const float4*)(lastc + b*256 + p0);
    float4 lcb = *(const float4*)(lastc + b*256 + p0 + 4);
    int   lw[8] = {lwa.x,lwa.y,lwa.z,lwa.w,lwb.x,lwb.y,lwb.z,lwb.w};
    float lc[8] = {lca.x,lca.y,lca.z,lca.w,lcb.x,lcb.y,lcb.z,lcb.w};
    float v[8];
    if (f32){
      float4 s0 = *(const float4*)((const float*)st0 + i0);
      float4 s1 = *(const float4*)((const float*)st0 + i0 + 4);
      v[0]=s0.x; v[1]=s0.y; v[2]=s0.z; v[3]=s0.w;
      v[4]=s1.x; v[5]=s1.y; v[6]=s1.z; v[7]=s1.w;
    } else {
      short8v s = *(const short8v*)((const u16*)st0 + i0);
      #pragma unroll
      for (int k = 0; k < 8; ++k) v[k] = bfv((u16)s[k]);
    }
    #pragma unroll
    for (int k = 0; k < 8; ++k){
      if (lw[k] >= 0) v[k] = H[(size_t)(lw[k]*32 + b)*MAPD + c];
      v[k] *= lc[k];
    }
    if (f32){
      float4 o0 = {v[0],v[1],v[2],v[3]}, o1 = {v[4],v[5],v[6],v[7]};
      float* op = (float*)out + 6144 + i0;
      *(float4*)op = o0; *(float4*)(op+4) = o1;
    } else {
      ushort4 o0, o1;
      o0.x=fbf(v[0]); o0.y=fbf(v[1]); o0.z=fbf(v[2]); o0.w=fbf(v[3]);
      o1.x=fbf(v[4]); o1.y=fbf(v[5]); o1.z=fbf(v[6]); o1.w=fbf(v[7]);
      u16* op = (u16*)out + 6144 + i0;
      *(ushort4*)op = o0; *(ushort4*)(op+4) = o1;
    }
  }
}

extern "C" void kernel_launch(void* const* d_in, const int* in_sizes, int n_in,
                              void* d_out, int out_size, void* d_ws, size_t ws_size,
                              hipStream_t stream) {
  (void)in_sizes; (void)n_in; (void)out_size; (void)ws_size;
  const void* image = d_in[0];
  const int*  lact  = (const int*)d_in[1];
  const int*  pos   = (const int*)d_in[2];
  const void* done  = d_in[3];
  const void* st0   = d_in[4];
  const void* c1w = d_in[5];  const void* c1b = d_in[6];
  const void* c2w = d_in[7];  const void* c2b = d_in[8];
  const void* c3w = d_in[9];  const void* c3b = d_in[10];
  const void* fcw = d_in[11]; const void* fcb = d_in[12];
  const void* pw1 = d_in[13]; const void* pb1 = d_in[14];
  const void* pw2 = d_in[15]; const void* pb2 = d_in[16];
  const void* vw1 = d_in[17]; const void* vb1 = d_in[18];
  const void* vw2 = d_in[19]; const void* vb2 = d_in[20];
  char* ws = (char*)d_ws;

  // workspace (~60.5 MB). No live overlays.
  u16*   WT    = (u16*)  (ws + 0);           // 33,882,112
  float* H     = (float*)(ws + 33882368);    // 2,117,632
  float* YI    = (float*)(ws + 36000256);    // 16,384
  u16*   PARTB = (u16*)  (ws + 36016640);    // 8,388,608
  int*   PREV  = (int*)  (ws + 44405248);
  float* COEF  = (float*)(ws + 44409344);
  int*   LASTW = (int*)  (ws + 44413440);
  float* LASTC = (float*)(ws + 44446208);
  u16*   W1F   = (u16*)  (ws + 44479232);    // 12,288
  u16*   W2F   = (u16*)  (ws + 44491520);    // 65,536
  u16*   W3F   = (u16*)  (ws + 44557056);    // 73,728
  u16*   FWF   = (u16*)  (ws + 44630784);    // 1,048,576
  u16*   ST0T  = (u16*)  (ws + 45679360);    // 8,470,528 -> 54,149,888
  u16*   C     = (u16*)  (ws + 54149888);    // 2,097,152 -> 56,247,040
  float* DLT8  = (float*)(ws + 56247040);    // 4,194,304 -> 60,441,344

  k_A      <<<1754, 256, 0, stream>>>(image, pw1, vw1, WT, c1w, c2w, c3w, fcw, st0,
                                      W1F, W2F, W3F, FWF, ST0T,
                                      pos, done, lact, PREV, COEF, H, LASTW, LASTC);
  k_conv123<<<1024, 256, 0, stream>>>(image, W1F, c1b, W2F, c2b, W3F, c3b, C);
  k_C      <<<1536, 256, 0, stream>>>(image, ST0T, WT, PARTB, C, FWF, fcb, H);
  k_D      <<<2112, 256, 0, stream>>>(image, H, WT, ST0T, pos, done, PREV, COEF, DLT8, PARTB, YI);
  k_E      <<<2100, 256, 0, stream>>>(image, YI, DLT8, done, pb1, vb1, pw2, pb2, vw2, vb2,
                                      H, st0, LASTW, LASTC, d_out);
}

// Round 10
// 317.204 us; speedup vs baseline: 1.0462x; 1.0167x over previous
//
#include <hip/hip_runtime.h>

#define T_ 32
#define B_ 32
#define MAPD 517
#define P_ 256
#define FLATD (MAPD*P_)   // 132352
#define TBN (T_*B_)       // 1024

typedef unsigned short u16;
typedef unsigned int u32;
typedef __attribute__((ext_vector_type(4))) short short4v;
typedef __attribute__((ext_vector_type(8))) short short8v;
typedef __attribute__((ext_vector_type(4))) float f32x4;
typedef __attribute__((ext_vector_type(2))) float f32x2;
typedef __attribute__((ext_vector_type(4))) u32 u32x4;

__device__ __forceinline__ float bfv(u16 u){ u32 x = ((u32)u)<<16; return __uint_as_float(x); }
__device__ __forceinline__ u16 fbf(float f){
  u32 x = __float_as_uint(f);
  return (u16)((x + 0x7fffu + ((x>>16)&1u))>>16);
}
template<bool F32> __device__ __forceinline__ float ld(const void* p, size_t i){
  if constexpr (F32) return ((const float*)p)[i];
  else               return bfv(((const u16*)p)[i]);
}
__device__ __forceinline__ float ldf(bool f32, const void* p, size_t i){
  return f32 ? ((const float*)p)[i] : bfv(((const u16*)p)[i]);
}

// ---- inline dtype probe: per-wave, no barrier ----
__device__ __forceinline__ bool probe_f32(const void* img){
  int lane = threadIdx.x & 63;
  ushort4 v = ((const ushort4*)img)[lane];      // lanes cover first 256 u16
  int c = (v.x <= 0x4380u) + (v.y <= 0x4380u) + (v.z <= 0x4380u) + (v.w <= 0x4380u);
  #pragma unroll
  for (int off = 32; off > 0; off >>= 1) c += __shfl_xor(c, off, 64);
  return c < 240;
}

// ================= k_A: wt-transpose (1034) + prep (588) + meta (36) =================
// Static LDS reduced to 18,464 B -> 8 blocks/CU (was 32 KB -> 5 blocks/CU).
// wt tile split into two p-halves of 64x64 u32 (16 KB each).
template<bool F32> __device__ void wt_body(int lbid, const void* pw1, const void* vw1,
                                           u16* wt, u32* tile){
  int c  = lbid >> 1;
  int ph = lbid & 1;
  for (int half = 0; half < 2; ++half){
    // phase 1: 512 tasks (2 its): jp in [0,64), pg' in [0,8)
    for (int it = 0; it < 2; ++it){
      int idx = it*256 + threadIdx.x;        // [0,512)
      int jp = idx >> 3, pgl = idx & 7;      // pgl: local pp-group of 8
      int j0 = jp*2;
      const void* w = (j0 < 64) ? pw1 : vw1;
      int jj0 = (j0 < 64) ? j0 : j0-64;
      size_t base0 = (size_t)jj0*FLATD + c*P_ + ph*128 + half*64 + pgl*8;
      size_t base1 = base0 + FLATD;
      u16 a[8], b[8];
      if constexpr (F32){
        const float* f = (const float*)w;
        float4 a0 = *(const float4*)(f + base0), a1 = *(const float4*)(f + base0 + 4);
        float4 b0 = *(const float4*)(f + base1), b1 = *(const float4*)(f + base1 + 4);
        a[0]=fbf(a0.x); a[1]=fbf(a0.y); a[2]=fbf(a0.z); a[3]=fbf(a0.w);
        a[4]=fbf(a1.x); a[5]=fbf(a1.y); a[6]=fbf(a1.z); a[7]=fbf(a1.w);
        b[0]=fbf(b0.x); b[1]=fbf(b0.y); b[2]=fbf(b0.z); b[3]=fbf(b0.w);
        b[4]=fbf(b1.x); b[5]=fbf(b1.y); b[6]=fbf(b1.z); b[7]=fbf(b1.w);
      } else {
        short8v va = *(const short8v*)((const u16*)w + base0);
        short8v vb = *(const short8v*)((const u16*)w + base1);
        #pragma unroll
        for (int k = 0; k < 8; ++k){ a[k] = (u16)va[k]; b[k] = (u16)vb[k]; }
      }
      int slot = (jp >> 2) ^ (half*8 + pgl);   // [0,16)
      int sub  = jp & 3;
      #pragma unroll
      for (int k = 0; k < 8; ++k){
        int ppl = pgl*8 + k;                   // local pp [0,64)
        tile[ppl*64 + slot*4 + sub] = (u32)a[k] | ((u32)b[k] << 16);
      }
    }
    __syncthreads();
    // phase 2: 1024 tasks (4 its): ppl in [0,64), jb in [0,16)
    for (int it = 0; it < 4; ++it){
      int idx = it*256 + threadIdx.x;        // [0,1024)
      int ppl = idx >> 4, jb = idx & 15;
      int slot = jb ^ (half*8 + (ppl >> 3));
      u32x4 v = *(const u32x4*)(tile + ppl*64 + slot*4);
      int p = ph*128 + half*64 + ppl;
      *(u32x4*)(wt + ((size_t)p*MAPD + c)*128 + jb*8) = v;
    }
    __syncthreads();
  }
}

__device__ void prep_body(bool f32, int bid, const void* c1w, const void* c2w, const void* c3w,
                          const void* fcw, const void* st0,
                          u16* W1F, u16* W2F, u16* W3F, u16* FWF, u16* ST0T, char* smem_){
  int tid = threadIdx.x;
  if (bid < 24){
    int idx = bid*256 + tid;                   // 6144
    int j = idx & 7, l = (idx>>3) & 63, t = idx>>9;
    int nt = t/6, s = t - nt*6;
    int oc = nt*16 + (l&15);
    int kk = 8*(4*s + (l>>4)) + j;
    float v = ldf(f32, c1w, oc*192+kk);
    W1F[idx] = fbf(v);
  } else if (bid < 152){
    int idx = (bid-24)*256 + tid;              // 32768
    int j = idx & 7, l = (idx>>3) & 63, s = (idx>>9) & 15, nt = idx>>13;
    int oc = nt*16 + (l&15);
    int cin = (l>>4)*8 + j;
    int src = oc*512 + cin*16 + (s>>2)*4 + (s&3);
    W2F[idx] = fbf(ldf(f32, c2w, src));
  } else if (bid < 296){
    int idx = (bid-152)*256 + tid;             // 36864
    int j = idx & 7, l = (idx>>3) & 63, t = idx>>9;   // t = nt*18+s
    int nt = t/18, s = t - nt*18;
    int oc = nt*16 + (l&15);
    int c = (s&1)*32 + (l>>4)*8 + j;
    int src = oc*576 + c*9 + (s>>1);
    W3F[idx] = fbf(ldf(f32, c3w, src));
  } else if (bid < 328){
    // FWF via vectorized fcw reads + LDS exchange. Block = one nt (16 o-rows).
    // kr = 16m+r (r in [0,16)) <-> kc = 64r+m; kt = 2r+(m>>5);
    // l = ((m>>3)&3)*16 + o_l; j = m&7. Reads: 16 consecutive kr per thread.
    u16* tile = (u16*)smem_;                   // [16 r][512] u16 = 16 KB
    int nt = bid - 296;
    int ol = tid >> 4;                         // o within nt
    int o  = nt*16 + ol;
    for (int par = 0; par < 2; ++par){
      for (int it = 0; it < 2; ++it){
        int m = par*32 + it*16 + (tid & 15);
        int col = (((m>>3)&3)*16 + ol)*8 + (m&7);
        u16 v[16];
        if (f32){
          const float* f = (const float*)fcw + (size_t)o*1024 + 16*m;
          #pragma unroll
          for (int q = 0; q < 4; ++q){
            float4 x = *(const float4*)(f + q*4);
            v[q*4+0]=fbf(x.x); v[q*4+1]=fbf(x.y); v[q*4+2]=fbf(x.z); v[q*4+3]=fbf(x.w);
          }
        } else {
          const u16* f = (const u16*)fcw + (size_t)o*1024 + 16*m;
          short8v x0 = *(const short8v*)f;
          short8v x1 = *(const short8v*)(f + 8);
          #pragma unroll
          for (int q = 0; q < 8; ++q){ v[q] = (u16)x0[q]; v[8+q] = (u16)x1[q]; }
        }
        #pragma unroll
        for (int r = 0; r < 16; ++r)
          tile[r*512 + col] = v[r];
      }
      __syncthreads();
      // flush: 16 rows -> frags nt*32 + 2*row + par, 1 KB contiguous each
      for (int it = 0; it < 4; ++it){
        int idx = it*256 + tid;                // [0,1024)
        int row = idx >> 6, colv = idx & 63;
        u32x4 w = *(const u32x4*)((const u32*)tile + row*256 + colv*4);
        int frag = nt*32 + row*2 + par;
        *(u32x4*)(FWF + (size_t)frag*512 + colv*8) = w;
      }
      __syncthreads();
    }
  } else {
    // ST0T[p][c][b] transpose — vectorized both sides, pad-36 LDS, rotated write order.
    u16* tile = (u16*)smem_;                   // [ci<4][pl<64] stride 36 u16 + b
    int b0 = bid - 328;                        // 260 blocks
    int c0 = (b0 >> 2)*8, p0 = (b0 & 3)*64;
    for (int half = 0; half < 2; ++half){
      int ch = c0 + half*4;
      for (int it = 0; it < 4; ++it){
        int idx = it*256 + tid;                // [0,1024)
        int pg = idx & 7, b = (idx>>3) & 31, ci = idx >> 8;   // ci 0..3
        int c = ch + ci;
        u16 v[8];
        if (c < MAPD){
          size_t src = ((size_t)b*MAPD + c)*256 + p0 + pg*8;
          if (f32){
            const float* f = (const float*)st0;
            float4 x0 = *(const float4*)(f + src), x1 = *(const float4*)(f + src + 4);
            v[0]=fbf(x0.x); v[1]=fbf(x0.y); v[2]=fbf(x0.z); v[3]=fbf(x0.w);
            v[4]=fbf(x1.x); v[5]=fbf(x1.y); v[6]=fbf(x1.z); v[7]=fbf(x1.w);
          } else {
            short8v x = *(const short8v*)((const u16*)st0 + src);
            #pragma unroll
            for (int k = 0; k < 8; ++k) v[k] = (u16)x[k];
          }
        } else {
          #pragma unroll
          for (int k = 0; k < 8; ++k) v[k] = 0;
        }
        #pragma unroll
        for (int kk = 0; kk < 8; ++kk){
          int k2 = (kk + pg) & 7;
          tile[ci*2304 + (pg*8 + k2)*36 + b] = v[k2];
        }
      }
      __syncthreads();
      for (int it = 0; it < 8; ++it){
        int idx = it*256 + tid;                // [0,2048)
        int bq = idx & 7, pl = (idx>>3) & 63, ci = idx >> 9;  // ci 0..3
        int c = ch + ci;
        if (c < MAPD){
          ushort4 v = *(const ushort4*)(tile + ci*2304 + pl*36 + bq*4);
          *(ushort4*)(ST0T + ((size_t)(p0+pl)*MAPD + c)*32 + bq*4) = v;
        }
      }
      __syncthreads();
    }
  }
}

__device__ void meta_body(bool f32, int bid, const int* pos, const void* done, const int* lact,
                          int* prev, float* coef, float* H, int* lastw, float* lastc){
  if (bid < 4){
    int i = bid*256 + threadIdx.x;
    int t = i >> 5, b = i & 31;
    int p = pos[i*2]*16 + pos[i*2+1];
    int pv = -1;
    for (int s = t-1; s >= 0; --s){
      int n = s*32 + b;
      if (pos[n*2]*16 + pos[n*2+1] == p){ pv = s; break; }
    }
    float cf = 1.f;
    for (int s = (pv<0?0:pv+1); s <= t-1; ++s)
      cf *= (1.f - ldf(f32, done, s*32+b));
    prev[i] = pv; coef[i] = cf;
    int la = lact[i];
    #pragma unroll
    for (int a = 0; a < 5; ++a) H[(size_t)i*MAPD + 512 + a] = (la == a) ? 1.f : 0.f;
  } else {
    int i = (bid-4)*256 + threadIdx.x;
    int b = i >> 8, p = i & 255;
    int lw = -1;
    for (int s = T_-1; s >= 0; --s){
      int n = s*32 + b;
      if (pos[n*2]*16 + pos[n*2+1] == p){ lw = s; break; }
    }
    float cf = 1.f;
    for (int s = (lw<0?0:lw+1); s < T_; ++s)
      cf *= (1.f - ldf(f32, done, s*32+b));
    lastw[i] = lw; lastc[i] = cf;
  }
}

__global__ __launch_bounds__(256) void k_A(const void* image,
                                           const void* pw1, const void* vw1, u16* wt,
                                           const void* c1w, const void* c2w, const void* c3w,
                                           const void* fcw, const void* st0,
                                           u16* W1F, u16* W2F, u16* W3F, u16* FWF, u16* ST0T,
                                           const int* pos, const void* done, const int* lact,
                                           int* prev, float* coef, float* H, int* lastw, float* lastc){
  __shared__ __align__(16) char smem_[18464];   // <- 8 blocks/CU
  bool f32 = probe_f32(image);
  int bid = blockIdx.x;
  if (bid < 1034){
    if (f32) wt_body<true>(bid, pw1, vw1, wt, (u32*)smem_);
    else     wt_body<false>(bid, pw1, vw1, wt, (u32*)smem_);
  } else if (bid < 1622){
    prep_body(f32, bid-1034, c1w, c2w, c3w, fcw, st0, W1F, W2F, W3F, FWF, ST0T, smem_);
  } else {
    meta_body(f32, bid-1622, pos, done, lact, prev, coef, H, lastw, lastc);
  }
}

// ================= k_conv123: fused convs =================
__global__ __launch_bounds__(256) void k_conv123(const void* img,
                                                 const u16* __restrict__ W1F, const void* b1,
                                                 const u16* __restrict__ W2F, const void* b2,
                                                 const u16* __restrict__ W3F, const void* b3,
                                                 u16* __restrict__ out){
  __shared__ __align__(16) u16 smem[19488];
  u16* sImg = smem;            // 12288 u16
  u16* sA   = smem + 12288;    // 7200 u16
  u16* sBv  = smem;            // 2304 u16, overlays sImg after conv1
  bool f32 = probe_f32(img);
  int n = blockIdx.x, tid = threadIdx.x;
  if (f32){
    const float4* ip = (const float4*)((const float*)img + (size_t)n*12288);
    for (int i = tid; i < 3072; i += 256){
      float4 v = ip[i];
      ushort4 u; u.x = fbf(v.x); u.y = fbf(v.y); u.z = fbf(v.z); u.w = fbf(v.w);
      int L = i*4;
      int addr = (L & ~63) | (((L & 63) + (((L >> 6) & 3) << 4)) & 63);
      *(ushort4*)(sImg + addr) = u;
    }
  } else {
    const ushort4* ip = (const ushort4*)((const u16*)img + (size_t)n*12288);
    for (int i = tid; i < 3072; i += 256){
      ushort4 u = ip[i];
      int L = i*4;
      int addr = (L & ~63) | (((L & 63) + (((L >> 6) & 3) << 4)) & 63);
      *(ushort4*)(sImg + addr) = u;
    }
  }
  int wv = tid >> 6, lane = tid & 63;
  int mi = lane & 15, q = lane >> 4;

  short8v bfr1[2][6];
  #pragma unroll
  for (int nt = 0; nt < 2; ++nt)
    #pragma unroll
    for (int s = 0; s < 6; ++s)
      bfr1[nt][s] = ((const short8v*)W1F)[(nt*6+s)*64 + lane];
  float b1v[2];
  #pragma unroll
  for (int nt = 0; nt < 2; ++nt)
    b1v[nt] = ldf(f32, b1, nt*16+mi);
  __syncthreads();

  {
    f32x4 acc[4][2];
    #pragma unroll
    for (int mt = 0; mt < 4; ++mt)
      #pragma unroll
      for (int nt = 0; nt < 2; ++nt)
        acc[mt][nt] = (f32x4){0.f,0.f,0.f,0.f};
    int base[4];
    #pragma unroll
    for (int mt = 0; mt < 4; ++mt){
      int m = (wv*4+mt)*16 + mi;
      int mc = m < 225 ? m : 224;
      int oy = mc/15, ox = mc - oy*15;
      base[mt] = oy*256 + ox*4;
    }
    for (int s = 0; s < 6; ++s){
      int cky = 4*s + q;
      int off = (cky >> 3)*4096 + (cky & 7)*64;
      #pragma unroll
      for (int mt = 0; mt < 4; ++mt){
        int Lb = base[mt] + off;
        const u16* rp = sImg + (Lb & ~63);
        int x0 = Lb & 63;
        int rot = ((Lb >> 6) & 3) << 4;
        short4v lo = *(const short4v*)(rp + ((x0 + rot) & 63));
        short4v hi = *(const short4v*)(rp + ((x0 + 4 + rot) & 63));
        short8v a = __builtin_shufflevector(lo, hi, 0,1,2,3,4,5,6,7);
        acc[mt][0] = __builtin_amdgcn_mfma_f32_16x16x32_bf16(a, bfr1[0][s], acc[mt][0], 0,0,0);
        acc[mt][1] = __builtin_amdgcn_mfma_f32_16x16x32_bf16(a, bfr1[1][s], acc[mt][1], 0,0,0);
      }
    }
    __syncthreads();   // sImg reads done before sBv (alias) writes in conv2
    #pragma unroll
    for (int mt = 0; mt < 4; ++mt){
      int mrow0 = (wv*4+mt)*16 + q*4;
      #pragma unroll
      for (int nt = 0; nt < 2; ++nt){
        int oc = nt*16 + mi;
        #pragma unroll
        for (int r = 0; r < 4; ++r){
          int m = mrow0 + r;
          if (m < 225){
            int g = ((oc >> 3) ^ ((m >> 1) & 3)) << 3;
            sA[m*32 + g + (oc & 7)] = fbf(fmaxf(acc[mt][nt][r] + b1v[nt], 0.f));
          }
        }
      }
    }
  }
  __syncthreads();

  {
    short8v bfr2[16];
    #pragma unroll
    for (int s = 0; s < 16; ++s)
      bfr2[s] = ((const short8v*)W2F)[(wv*16+s)*64 + lane];
    int oc = wv*16 + mi;
    float bv = ldf(f32, b2, oc);
    f32x4 acc[3];
    #pragma unroll
    for (int mt = 0; mt < 3; ++mt) acc[mt] = (f32x4){0.f,0.f,0.f,0.f};
    int pixb[3];
    #pragma unroll
    for (int mt = 0; mt < 3; ++mt){
      int m = mt*16 + mi; if (m > 35) m = 35;
      int oy = m/6, ox = m - oy*6;
      pixb[mt] = oy*30 + ox*2;
    }
    #pragma unroll
    for (int s = 0; s < 16; ++s){
      int dp = (s>>2)*15 + (s&3);
      #pragma unroll
      for (int mt = 0; mt < 3; ++mt){
        int pix = pixb[mt] + dp;
        int g = (q ^ ((pix >> 1) & 3)) << 3;
        short8v a = *(const short8v*)(sA + pix*32 + g);
        acc[mt] = __builtin_amdgcn_mfma_f32_16x16x32_bf16(a, bfr2[s], acc[mt], 0,0,0);
      }
    }
    __syncthreads();
    #pragma unroll
    for (int mt = 0; mt < 3; ++mt)
      #pragma unroll
      for (int r = 0; r < 4; ++r){
        int m = mt*16 + q*4 + r;
        if (m < 36){
          int g = ((oc >> 3) ^ (m & 7)) << 3;
          sBv[m*64 + g + (oc & 7)] = fbf(fmaxf(acc[mt][r] + bv, 0.f));
        }
      }
  }
  __syncthreads();

  {
    int oy = mi >> 2, ox = mi & 3;
    int oc = wv*16 + mi;
    float bv = ldf(f32, b3, oc);
    short8v bfr3[18];
    #pragma unroll
    for (int s = 0; s < 18; ++s)
      bfr3[s] = ((const short8v*)W3F)[(wv*18+s)*64 + lane];
    f32x4 acc = (f32x4){0.f,0.f,0.f,0.f};
    #pragma unroll
    for (int s = 0; s < 18; ++s){
      int pair = s >> 1, ky = pair/3, kx = pair - ky*3;
      int pix = (oy+ky)*6 + ox+kx;
      int g = ((((s & 1) << 2) | q) ^ (pix & 7)) << 3;
      short8v a = *(const short8v*)(sBv + pix*64 + g);
      acc = __builtin_amdgcn_mfma_f32_16x16x32_bf16(a, bfr3[s], acc, 0,0,0);
    }
    u16* ob = out + (size_t)n*1024;
    #pragma unroll
    for (int r = 0; r < 4; ++r)
      ob[(q*4+r)*64 + oc] = fbf(fmaxf(acc[r] + bv, 0.f));
  }
}

// ================= k_C: yinit (1024) + fc (512) =================
template<int CLEN>
__device__ __forceinline__ void yloop(const u16* __restrict__ wp, const float* __restrict__ sSb,
                                      float (&acc)[8][2]){
  #pragma unroll 10
  for (int c = 0; c < CLEN; ++c){
    u32 w = *(const u32*)(wp + (size_t)c*128);
    float w0 = bfv((u16)(w & 0xffffu)), w1 = bfv((u16)(w >> 16));
    const float4* s4 = (const float4*)(sSb + c*32);
    float4 sa = s4[0], sb = s4[1];
    float sv[8] = {sa.x,sa.y,sa.z,sa.w,sb.x,sb.y,sb.z,sb.w};
    #pragma unroll
    for (int bb = 0; bb < 8; ++bb){
      acc[bb][0] += sv[bb]*w0;
      acc[bb][1] += sv[bb]*w1;
    }
  }
}
__device__ void yinit_body(int lbid, const u16* __restrict__ ST0T, const u16* __restrict__ wt,
                           u16* __restrict__ PARTB, float* sS){
  int p = lbid >> 2, cq = lbid & 3;
  int c0 = cq*130;
  int clen = (cq == 3) ? 127 : 130;
  const ushort4* ssrc = (const ushort4*)(ST0T + ((size_t)p*MAPD + c0)*32);
  int n4 = clen*8;
  for (int i = threadIdx.x; i < n4; i += 256){
    ushort4 u = ssrc[i];
    float4 f; f.x = bfv(u.x); f.y = bfv(u.y); f.z = bfv(u.z); f.w = bfv(u.w);
    *(float4*)(sS + i*4) = f;
  }
  __syncthreads();
  int jg = threadIdx.x & 63, bg = threadIdx.x >> 6;
  int j0 = jg*2, b0 = bg*8;
  const u16* wp = wt + ((size_t)p*MAPD + c0)*128 + j0;
  float acc[8][2] = {};
  if (cq < 3) yloop<130>(wp, sS + b0, acc);
  else        yloop<127>(wp, sS + b0, acc);
  u32* op = (u32*)(PARTB + (size_t)lbid*4096);
  #pragma unroll
  for (int bb = 0; bb < 8; ++bb){
    u32 pk = (u32)fbf(acc[bb][0]) | ((u32)fbf(acc[bb][1]) << 16);
    op[((b0+bb)*128 + j0) >> 1] = pk;
  }
}
__device__ void fc_body(int lbid, bool f32, const u16* __restrict__ C, const u16* __restrict__ FWF,
                        const void* fb, float* __restrict__ H){
  int wv = threadIdx.x >> 6, lane = threadIdx.x & 63;
  int mi = lane & 15, q = lane >> 4;
  int mt = lbid >> 3;               // 0..63
  int nt = (lbid & 7)*4 + wv;       // 0..31
  const u16* ap = C + (size_t)(mt*16 + mi)*1024 + q*8;
  const short8v* bp = (const short8v*)FWF + (size_t)nt*32*64 + lane;
  f32x4 acc0 = (f32x4){0.f,0.f,0.f,0.f};
  f32x4 acc1 = (f32x4){0.f,0.f,0.f,0.f};
  #pragma unroll
  for (int kt = 0; kt < 32; kt += 2){
    short8v a0 = *(const short8v*)(ap + kt*32);
    short8v b0 = bp[kt*64];
    short8v a1 = *(const short8v*)(ap + (kt+1)*32);
    short8v b1 = bp[(kt+1)*64];
    acc0 = __builtin_amdgcn_mfma_f32_16x16x32_bf16(a0, b0, acc0, 0,0,0);
    acc1 = __builtin_amdgcn_mfma_f32_16x16x32_bf16(a1, b1, acc1, 0,0,0);
  }
  int o = nt*16 + mi;
  float bv = ldf(f32, fb, o);
  #pragma unroll
  for (int r = 0; r < 4; ++r){
    int m = mt*16 + q*4 + r;
    H[(size_t)m*MAPD + o] = fmaxf(acc0[r] + acc1[r] + bv, 0.f);
  }
}
__global__ __launch_bounds__(256) void k_C(const void* image,
                                           const u16* __restrict__ ST0T, const u16* __restrict__ wt,
                                           u16* __restrict__ PARTB,
                                           const u16* __restrict__ C, const u16* __restrict__ FWF,
                                           const void* fb, float* __restrict__ H){
  __shared__ float sS[130*32];   // 16.6 KB (yinit branch)
  if (blockIdx.x < 1024){
    yinit_body(blockIdx.x, ST0T, wt, PARTB, sS);
  } else {
    bool f32 = probe_f32(image);
    fc_body(blockIdx.x - 1024, f32, C, FWF, fb, H);
  }
}

// ================= k_D: delta (2048 blocks x 2 units) + yred (64) =================
__device__ void delta_body(int obid, int ltid, float* diff, bool f32,
                           const float* __restrict__ H, const u16* __restrict__ wt,
                           const u16* __restrict__ st0t,
                           const int* __restrict__ pos, const void* done,
                           const int* __restrict__ prev, const float* __restrict__ coef,
                           float* __restrict__ dlt8){
  int n = obid >> 2, cq = obid & 3;
  int c0 = cq*130, clen = (cq == 3) ? 127 : 130;
  int b = n & 31;
  int p = pos[n*2]*16 + pos[n*2+1];
  float dn = ldf(f32, done, n);
  float m = 1.f - dn;
  int pv = prev[n];
  float cf = coef[n]*m;
  const float* hc = H + (size_t)n*MAPD + c0;
  for (int c = ltid; c < clen; c += 128){
    float old;
    if (pv >= 0) old = H[(size_t)(pv*32 + b)*MAPD + c0 + c];
    else         old = bfv(st0t[((size_t)p*MAPD + c0 + c)*32 + b]);
    diff[c] = hc[c] - cf*old;
  }
  __syncthreads();
  int half = ltid >> 6, jp = ltid & 63, j0 = jp*2;
  int hbase, hlen;
  if (cq == 3){ hbase = half*64; hlen = half ? 63 : 64; }
  else        { hbase = half*65; hlen = 65; }
  const u16* wp = wt + ((size_t)p*MAPD + c0 + hbase)*128 + j0;
  const float* dptr = diff + hbase;
  float a0 = 0.f, a1 = 0.f;
  int c = 0;
  for (; c + 4 <= hlen; c += 4){
    u32 w0 = *(const u32*)(wp + (size_t)(c+0)*128);
    u32 w1 = *(const u32*)(wp + (size_t)(c+1)*128);
    u32 w2 = *(const u32*)(wp + (size_t)(c+2)*128);
    u32 w3 = *(const u32*)(wp + (size_t)(c+3)*128);
    float d0 = dptr[c], d1 = dptr[c+1], d2 = dptr[c+2], d3 = dptr[c+3];
    a0 += d0*bfv((u16)(w0 & 0xffffu)) + d1*bfv((u16)(w1 & 0xffffu))
        + d2*bfv((u16)(w2 & 0xffffu)) + d3*bfv((u16)(w3 & 0xffffu));
    a1 += d0*bfv((u16)(w0 >> 16)) + d1*bfv((u16)(w1 >> 16))
        + d2*bfv((u16)(w2 >> 16)) + d3*bfv((u16)(w3 >> 16));
  }
  for (; c < hlen; ++c){
    u32 w = *(const u32*)(wp + (size_t)c*128);
    a0 += dptr[c]*bfv((u16)(w & 0xffffu));
    a1 += dptr[c]*bfv((u16)(w >> 16));
  }
  f32x2 st; st[0] = a0; st[1] = a1;
  *(f32x2*)(dlt8 + ((size_t)obid*2 + half)*128 + j0) = st;
}
__global__ __launch_bounds__(256) void k_D(const void* image,
                                           const float* __restrict__ H, const u16* __restrict__ wt,
                                           const u16* __restrict__ st0t,
                                           const int* __restrict__ pos, const void* done,
                                           const int* __restrict__ prev, const float* __restrict__ coef,
                                           float* __restrict__ dlt8,
                                           const u16* __restrict__ PARTB, float* __restrict__ YI){
  __shared__ float diff2[2][132];
  __shared__ float red[256];
  if (blockIdx.x < 2048){
    bool f32 = probe_f32(image);
    int sub = threadIdx.x >> 7;
    int obid = blockIdx.x*2 + sub;
    delta_body(obid, threadIdx.x & 127, diff2[sub], f32, H, wt, st0t, pos, done, prev, coef, dlt8);
  } else {
    int lbid = blockIdx.x - 2048;
    int o = lbid*64 + (threadIdx.x & 63);
    int kq = threadIdx.x >> 6;
    float s = 0.f;
    const u16* pp = PARTB + (size_t)kq*256*4096 + o;
    #pragma unroll 8
    for (int k = 0; k < 256; ++k) s += bfv(pp[(size_t)k*4096]);
    red[threadIdx.x] = s;
    __syncthreads();
    if (threadIdx.x < 64)
      YI[o] = red[threadIdx.x] + red[threadIdx.x+64] + red[threadIdx.x+128] + red[threadIdx.x+192];
  }
}

// ================= k_E: scan+heads (32, LDS-prefetched) + final (2068, vector st0) ========
__device__ void scan_heads_body(bool f32, const float* __restrict__ yi,
                                const float* __restrict__ dlt8, const void* done,
                                const void* pb1, const void* vb1,
                                const void* pw2, const void* pb2,
                                const void* vw2, const void* vb2, void* out,
                                float* sd, float* sm){
  int b = blockIdx.x;
  for (int it = 0; it < 16; ++it){
    int idx = it*256 + threadIdx.x;          // 4096 = 32t x 128j
    int t = idx >> 7, j = idx & 127;
    const float* dp = dlt8 + (size_t)(t*32 + b)*1024 + j;
    sd[idx] = dp[0] + dp[128] + dp[256] + dp[384]
            + dp[512] + dp[640] + dp[768] + dp[896];
  }
  if (threadIdx.x < 32) sm[threadIdx.x] = 1.f - ldf(f32, done, threadIdx.x*32 + b);
  __syncthreads();
  if (threadIdx.x >= 128) return;
  int j = threadIdx.x;
  int lane = j & 63;
  bool pol = j < 64;
  float y = yi[b*128 + j];
  float bias = pol ? ldf(f32, pb1, j) : ldf(f32, vb1, j-64);
  float w2[5];
  if (pol){
    #pragma unroll
    for (int jj = 0; jj < 5; ++jj) w2[jj] = ldf(f32, pw2, jj*64 + lane);
  } else {
    w2[0] = ldf(f32, vw2, lane);
  }
  for (int t = 0; t < T_; ++t){
    int n = t*32 + b;
    y = sm[t]*y + sd[t*128 + j];
    float th = tanhf(y + bias);
    if (pol){
      float s0 = th*w2[0], s1 = th*w2[1], s2 = th*w2[2], s3 = th*w2[3], s4 = th*w2[4];
      #pragma unroll
      for (int off = 32; off > 0; off >>= 1){
        s0 += __shfl_xor(s0, off, 64);
        s1 += __shfl_xor(s1, off, 64);
        s2 += __shfl_xor(s2, off, 64);
        s3 += __shfl_xor(s3, off, 64);
        s4 += __shfl_xor(s4, off, 64);
      }
      if (lane == 0){
        float sv[5] = {s0,s1,s2,s3,s4};
        #pragma unroll
        for (int jj = 0; jj < 5; ++jj){
          float s = sv[jj] + ldf(f32, pb2, jj);
          if (f32) ((float*)out)[n*5 + jj] = s; else ((u16*)out)[n*5 + jj] = fbf(s);
        }
      }
    } else {
      float s = th*w2[0];
      #pragma unroll
      for (int off = 32; off > 0; off >>= 1) s += __shfl_xor(s, off, 64);
      if (lane == 0){
        s += ldf(f32, vb2, 0);
        if (f32) ((float*)out)[5120 + n] = s; else ((u16*)out)[5120 + n] = fbf(s);
      }
    }
  }
}
__global__ __launch_bounds__(256) void k_E(const void* image,
                                           const float* __restrict__ yi, const float* __restrict__ dlt8,
                                           const void* done, const void* pb1, const void* vb1,
                                           const void* pw2, const void* pb2,
                                           const void* vw2, const void* vb2,
                                           const float* __restrict__ H, const void* st0,
                                           const int* __restrict__ lastw, const float* __restrict__ lastc,
                                           void* out){
  __shared__ float sd[32*128];   // 16 KB (scan branch)
  __shared__ float sm[32];
  bool f32 = probe_f32(image);
  if (blockIdx.x < 32){
    scan_heads_body(f32, yi, dlt8, done, pb1, vb1, pw2, pb2, vw2, vb2, out, sd, sm);
  } else {
    size_t i0 = (size_t)(blockIdx.x - 32)*2048 + (size_t)threadIdx.x*8;
    int b = (int)(i0 / FLATD);
    int r = (int)(i0 - (size_t)b*FLATD);
    int c = r >> 8, p0 = r & 255;
    int4 lwa = *(const int4*)(lastw + b*256 + p0);
    int4 lwb = *(const int4*)(lastw + b*256 + p0 + 4);
    float4 lca = *(const float4*)(lastc + b*256 + p0);
    float4 lcb = *(const float4*)(lastc + b*256 + p0 + 4);
    int   lw[8] = {lwa.x,lwa.y,lwa.z,lwa.w,lwb.x,lwb.y,lwb.z,lwb.w};
    float lc[8] = {lca.x,lca.y,lca.z,lca.w,lcb.x,lcb.y,lcb.z,lcb.w};
    float v[8];
    if (f32){
      float4 s0 = *(const float4*)((const float*)st0 + i0);
      float4 s1 = *(const float4*)((const float*)st0 + i0 + 4);
      v[0]=s0.x; v[1]=s0.y; v[2]=s0.z; v[3]=s0.w;
      v[4]=s1.x; v[5]=s1.y; v[6]=s1.z; v[7]=s1.w;
    } else {
      short8v s = *(const short8v*)((const u16*)st0 + i0);
      #pragma unroll
      for (int k = 0; k < 8; ++k) v[k] = bfv((u16)s[k]);
    }
    #pragma unroll
    for (int k = 0; k < 8; ++k){
      if (lw[k] >= 0) v[k] = H[(size_t)(lw[k]*32 + b)*MAPD + c];
      v[k] *= lc[k];
    }
    if (f32){
      float4 o0 = {v[0],v[1],v[2],v[3]}, o1 = {v[4],v[5],v[6],v[7]};
      float* op = (float*)out + 6144 + i0;
      *(float4*)op = o0; *(float4*)(op+4) = o1;
    } else {
      ushort4 o0, o1;
      o0.x=fbf(v[0]); o0.y=fbf(v[1]); o0.z=fbf(v[2]); o0.w=fbf(v[3]);
      o1.x=fbf(v[4]); o1.y=fbf(v[5]); o1.z=fbf(v[6]); o1.w=fbf(v[7]);
      u16* op = (u16*)out + 6144 + i0;
      *(ushort4*)op = o0; *(ushort4*)(op+4) = o1;
    }
  }
}

extern "C" void kernel_launch(void* const* d_in, const int* in_sizes, int n_in,
                              void* d_out, int out_size, void* d_ws, size_t ws_size,
                              hipStream_t stream) {
  (void)in_sizes; (void)n_in; (void)out_size; (void)ws_size;
  const void* image = d_in[0];
  const int*  lact  = (const int*)d_in[1];
  const int*  pos   = (const int*)d_in[2];
  const void* done  = d_in[3];
  const void* st0   = d_in[4];
  const void* c1w = d_in[5];  const void* c1b = d_in[6];
  const void* c2w = d_in[7];  const void* c2b = d_in[8];
  const void* c3w = d_in[9];  const void* c3b = d_in[10];
  const void* fcw = d_in[11]; const void* fcb = d_in[12];
  const void* pw1 = d_in[13]; const void* pb1 = d_in[14];
  const void* pw2 = d_in[15]; const void* pb2 = d_in[16];
  const void* vw1 = d_in[17]; const void* vb1 = d_in[18];
  const void* vw2 = d_in[19]; const void* vb2 = d_in[20];
  char* ws = (char*)d_ws;

  // workspace (~60.5 MB). No live overlays.
  u16*   WT    = (u16*)  (ws + 0);           // 33,882,112
  float* H     = (float*)(ws + 33882368);    // 2,117,632
  float* YI    = (float*)(ws + 36000256);    // 16,384
  u16*   PARTB = (u16*)  (ws + 36016640);    // 8,388,608
  int*   PREV  = (int*)  (ws + 44405248);
  float* COEF  = (float*)(ws + 44409344);
  int*   LASTW = (int*)  (ws + 44413440);
  float* LASTC = (float*)(ws + 44446208);
  u16*   W1F   = (u16*)  (ws + 44479232);    // 12,288
  u16*   W2F   = (u16*)  (ws + 44491520);    // 65,536
  u16*   W3F   = (u16*)  (ws + 44557056);    // 73,728
  u16*   FWF   = (u16*)  (ws + 44630784);    // 1,048,576
  u16*   ST0T  = (u16*)  (ws + 45679360);    // 8,470,528 -> 54,149,888
  u16*   C     = (u16*)  (ws + 54149888);    // 2,097,152 -> 56,247,040
  float* DLT8  = (float*)(ws + 56247040);    // 4,194,304 -> 60,441,344

  k_A      <<<1658, 256, 0, stream>>>(image, pw1, vw1, WT, c1w, c2w, c3w, fcw, st0,
                                      W1F, W2F, W3F, FWF, ST0T,
                                      pos, done, lact, PREV, COEF, H, LASTW, LASTC);
  k_conv123<<<1024, 256, 0, stream>>>(image, W1F, c1b, W2F, c2b, W3F, c3b, C);
  k_C      <<<1536, 256, 0, stream>>>(image, ST0T, WT, PARTB, C, FWF, fcb, H);
  k_D      <<<2112, 256, 0, stream>>>(image, H, WT, ST0T, pos, done, PREV, COEF, DLT8, PARTB, YI);
  k_E      <<<2100, 256, 0, stream>>>(image, YI, DLT8, done, pb1, vb1, pw2, pb2, vw2, vb2,
                                      H, st0, LASTW, LASTC, d_out);
}